// Round 1
// baseline (9433.875 us; speedup 1.0000x reference)
//
#include <hip/hip_runtime.h>
#include <math.h>

// Problem constants
#define LAYERS 6
#define DMODEL 512
#define NHEAD 8
#define DHEAD 64
#define FFDIM 2048
#define BATCH 8
#define SEQ 1024
#define ROWS (BATCH * SEQ)   // 8192
#define EPS 1e-5f

// ---------------------------------------------------------------------------
// Positional scan: positions = cumsum(mask!=0) * (mask!=0), per batch row
// ---------------------------------------------------------------------------
__global__ void pos_scan_kernel(const int* __restrict__ mask, int* __restrict__ pos) {
    __shared__ int sm[SEQ];
    int b = blockIdx.x;
    int t = threadIdx.x;
    int v = (mask[b * SEQ + t] != 0) ? 1 : 0;
    sm[t] = v;
    __syncthreads();
    for (int off = 1; off < SEQ; off <<= 1) {
        int add = (t >= off) ? sm[t - off] : 0;
        __syncthreads();
        sm[t] += add;
        __syncthreads();
    }
    pos[b * SEQ + t] = sm[t] * v;
}

// ---------------------------------------------------------------------------
// x = x_in + sin_pos_table[pos]   (table computed on the fly; pos==0 -> 0)
// one block per (b,s), 128 threads, 4 elems each
// ---------------------------------------------------------------------------
__global__ void add_pos_kernel(const float* __restrict__ xin, const int* __restrict__ pos,
                               float* __restrict__ xout) {
    int bs = blockIdx.x;
    int t = threadIdx.x;
    int p = pos[bs];
    int d0 = t * 4;
    const float C = -logf(10000.0f) * (1.0f / 255.0f);  // half-1 = 255
    float4 xv = *(const float4*)(xin + (size_t)bs * DMODEL + d0);
    float e[4];
#pragma unroll
    for (int j = 0; j < 4; ++j) {
        int d = d0 + j;
        if (p == 0) {
            e[j] = 0.0f;
        } else {
            int dd = (d < 256) ? d : d - 256;
            float freq = expf((float)dd * C);
            float ang = (float)p * freq;
            e[j] = (d < 256) ? sinf(ang) : cosf(ang);
        }
    }
    float4 ov;
    ov.x = xv.x + e[0]; ov.y = xv.y + e[1]; ov.z = xv.z + e[2]; ov.w = xv.w + e[3];
    *(float4*)(xout + (size_t)bs * DMODEL + d0) = ov;
}

// ---------------------------------------------------------------------------
// fp32 tiled GEMM: C[M,N] = A[M,K] @ B[K,N] (+bias) (+relu)
// 128x128 tile, BK=8, 256 threads, 8x8 micro-tile per thread
// M,N multiples of 128; K multiple of 8 (true for all shapes here)
// ---------------------------------------------------------------------------
template <bool BIAS, bool RELU>
__global__ __launch_bounds__(256) void gemm_kernel(const float* __restrict__ A,
                                                   const float* __restrict__ B,
                                                   const float* __restrict__ bias,
                                                   float* __restrict__ C,
                                                   int M, int N, int K) {
    __shared__ float As[8][132];  // +4 pad: <=2-way bank aliasing (free)
    __shared__ float Bs[8][132];
    const int t = threadIdx.x;
    const int n0 = blockIdx.x * 128;
    const int m0 = blockIdx.y * 128;
    const int tx = t & 15;
    const int ty = t >> 4;

    // A-load mapping: 128 rows x 8 k, one float4 per thread
    const int am = t >> 1;
    const int ak = (t & 1) * 4;
    // B-load mapping: 8 k x 128 cols, one float4 per thread
    const int bk = t >> 5;
    const int bn = (t & 31) * 4;

    const float* Aptr = A + (size_t)(m0 + am) * K + ak;
    const float* Bptr = B + (size_t)bk * N + n0 + bn;

    float acc[8][8] = {};

    for (int k0 = 0; k0 < K; k0 += 8) {
        float4 a4 = *(const float4*)(Aptr + k0);
        float4 b4 = *(const float4*)(Bptr + (size_t)k0 * N);
        As[ak + 0][am] = a4.x;
        As[ak + 1][am] = a4.y;
        As[ak + 2][am] = a4.z;
        As[ak + 3][am] = a4.w;
        *(float4*)&Bs[bk][bn] = b4;
        __syncthreads();
#pragma unroll
        for (int k = 0; k < 8; ++k) {
            float4 a0 = *(const float4*)&As[k][ty * 4];
            float4 a1 = *(const float4*)&As[k][ty * 4 + 64];
            float4 b0 = *(const float4*)&Bs[k][tx * 4];
            float4 b1 = *(const float4*)&Bs[k][tx * 4 + 64];
            float av[8] = {a0.x, a0.y, a0.z, a0.w, a1.x, a1.y, a1.z, a1.w};
            float bv[8] = {b0.x, b0.y, b0.z, b0.w, b1.x, b1.y, b1.z, b1.w};
#pragma unroll
            for (int i = 0; i < 8; ++i)
#pragma unroll
                for (int j = 0; j < 8; ++j) acc[i][j] += av[i] * bv[j];
        }
        __syncthreads();
    }

#pragma unroll
    for (int ih = 0; ih < 2; ++ih)
#pragma unroll
        for (int ii = 0; ii < 4; ++ii) {
            int m = m0 + ih * 64 + ty * 4 + ii;
#pragma unroll
            for (int jh = 0; jh < 2; ++jh) {
                int n = n0 + jh * 64 + tx * 4;
                float4 v;
                v.x = acc[ih * 4 + ii][jh * 4 + 0];
                v.y = acc[ih * 4 + ii][jh * 4 + 1];
                v.z = acc[ih * 4 + ii][jh * 4 + 2];
                v.w = acc[ih * 4 + ii][jh * 4 + 3];
                if (BIAS) {
                    v.x += bias[n]; v.y += bias[n + 1]; v.z += bias[n + 2]; v.w += bias[n + 3];
                }
                if (RELU) {
                    v.x = fmaxf(v.x, 0.f); v.y = fmaxf(v.y, 0.f);
                    v.z = fmaxf(v.z, 0.f); v.w = fmaxf(v.w, 0.f);
                }
                *(float4*)(C + (size_t)m * N + n) = v;
            }
        }
}

// ---------------------------------------------------------------------------
// Flash-style attention, fp32. Grid: (4 q-chunks, B*H). Block 256 = one q-row
// per thread. K/V staged in 64-key LDS tiles; online softmax per thread.
// qkv: [B*S, 3*D] rows (q | k | v), head h occupies cols h*64..h*64+63
// o:   [B*S, D] with head-major layout == [B,S,H,dh] flattened
// ---------------------------------------------------------------------------
__global__ __launch_bounds__(256) void attn_kernel(const float* __restrict__ qkv,
                                                   const int* __restrict__ mask,
                                                   float* __restrict__ o) {
    __shared__ float Ks[64][64];
    __shared__ float Vs[64][64];
    __shared__ int Ms[64];
    const int chunk = blockIdx.x;       // 0..3
    const int bh = blockIdx.y;          // 0..63
    const int b = bh >> 3;
    const int h = bh & 7;
    const int t = threadIdx.x;
    const int sq = chunk * 256 + t;     // q row within sequence

    const size_t rowq = (size_t)(b * SEQ + sq) * (3 * DMODEL) + h * DHEAD;
    float4 q[16];
#pragma unroll
    for (int i = 0; i < 16; ++i) q[i] = *(const float4*)(qkv + rowq + i * 4);

    float acc[64] = {};
    float mx = -1e30f;
    float l = 0.f;

    for (int kt = 0; kt < 16; ++kt) {
        __syncthreads();
#pragma unroll
        for (int i = 0; i < 4; ++i) {
            int idx = t + i * 256;
            int key = idx >> 4;
            int d4 = (idx & 15) * 4;
            size_t rowk = (size_t)(b * SEQ + kt * 64 + key) * (3 * DMODEL) + h * DHEAD + d4;
            *(float4*)&Ks[key][d4] = *(const float4*)(qkv + rowk + DMODEL);
            *(float4*)&Vs[key][d4] = *(const float4*)(qkv + rowk + 2 * DMODEL);
        }
        if (t < 64) Ms[t] = mask[b * SEQ + kt * 64 + t];
        __syncthreads();

        for (int kk = 0; kk < 64; ++kk) {
            if (Ms[kk] == 0) continue;  // masked key == -inf logit
            const float4* kr = (const float4*)Ks[kk];
            float s = 0.f;
#pragma unroll
            for (int i = 0; i < 16; ++i) {
                float4 kv = kr[i];
                s += q[i].x * kv.x + q[i].y * kv.y + q[i].z * kv.z + q[i].w * kv.w;
            }
            if (s > mx) {
                float f = __expf(mx - s);
                l *= f;
#pragma unroll
                for (int d = 0; d < 64; ++d) acc[d] *= f;
                mx = s;
            }
            float p = __expf(s - mx);
            l += p;
            const float4* vr = (const float4*)Vs[kk];
#pragma unroll
            for (int i = 0; i < 16; ++i) {
                float4 vv = vr[i];
                acc[i * 4 + 0] += p * vv.x;
                acc[i * 4 + 1] += p * vv.y;
                acc[i * 4 + 2] += p * vv.z;
                acc[i * 4 + 3] += p * vv.w;
            }
        }
    }

    float inv = 1.f / l;
    const size_t rowo = (size_t)(b * SEQ + sq) * DMODEL + h * DHEAD;
#pragma unroll
    for (int i = 0; i < 16; ++i) {
        float4 ov;
        ov.x = acc[i * 4 + 0] * inv;
        ov.y = acc[i * 4 + 1] * inv;
        ov.z = acc[i * 4 + 2] * inv;
        ov.w = acc[i * 4 + 3] * inv;
        *(float4*)(o + rowo + i * 4) = ov;
    }
}

// ---------------------------------------------------------------------------
// x = LayerNorm(tmp + x) * g + b   (in-place on x). One wave per row.
// ---------------------------------------------------------------------------
__global__ __launch_bounds__(64) void ln_kernel(const float* __restrict__ tmp,
                                                float* __restrict__ x,
                                                const float* __restrict__ g,
                                                const float* __restrict__ bta) {
    const int row = blockIdx.x;
    const int t = threadIdx.x;
    const size_t base = (size_t)row * DMODEL + t * 8;
    float4 x0 = *(const float4*)(x + base);
    float4 x1 = *(const float4*)(x + base + 4);
    float4 t0 = *(const float4*)(tmp + base);
    float4 t1 = *(const float4*)(tmp + base + 4);
    float v[8];
    v[0] = x0.x + t0.x; v[1] = x0.y + t0.y; v[2] = x0.z + t0.z; v[3] = x0.w + t0.w;
    v[4] = x1.x + t1.x; v[5] = x1.y + t1.y; v[6] = x1.z + t1.z; v[7] = x1.w + t1.w;
    float s = 0.f, sq = 0.f;
#pragma unroll
    for (int i = 0; i < 8; ++i) { s += v[i]; sq += v[i] * v[i]; }
#pragma unroll
    for (int off = 1; off < 64; off <<= 1) {
        s += __shfl_xor(s, off);
        sq += __shfl_xor(sq, off);
    }
    float mu = s * (1.0f / DMODEL);
    float var = sq * (1.0f / DMODEL) - mu * mu;
    float r = rsqrtf(var + EPS);
    float4 g0 = *(const float4*)(g + t * 8);
    float4 g1 = *(const float4*)(g + t * 8 + 4);
    float4 b0 = *(const float4*)(bta + t * 8);
    float4 b1 = *(const float4*)(bta + t * 8 + 4);
    float4 o0, o1;
    o0.x = (v[0] - mu) * r * g0.x + b0.x;
    o0.y = (v[1] - mu) * r * g0.y + b0.y;
    o0.z = (v[2] - mu) * r * g0.z + b0.z;
    o0.w = (v[3] - mu) * r * g0.w + b0.w;
    o1.x = (v[4] - mu) * r * g1.x + b1.x;
    o1.y = (v[5] - mu) * r * g1.y + b1.y;
    o1.z = (v[6] - mu) * r * g1.z + b1.z;
    o1.w = (v[7] - mu) * r * g1.w + b1.w;
    *(float4*)(x + base) = o0;
    *(float4*)(x + base + 4) = o1;
}

// ---------------------------------------------------------------------------
extern "C" void kernel_launch(void* const* d_in, const int* in_sizes, int n_in,
                              void* d_out, int out_size, void* d_ws, size_t ws_size,
                              hipStream_t stream) {
    const float* x_in  = (const float*)d_in[0];
    // d_in[1] char_ids, d_in[2] seq_len: unused by reference
    const int*   mask  = (const int*)d_in[3];
    const float* Wqkv  = (const float*)d_in[4];
    const float* Wfc   = (const float*)d_in[5];
    const float* bfc   = (const float*)d_in[6];
    const float* ln1_g = (const float*)d_in[7];
    const float* ln1_b = (const float*)d_in[8];
    const float* ln2_g = (const float*)d_in[9];
    const float* ln2_b = (const float*)d_in[10];
    const float* W1    = (const float*)d_in[11];
    const float* b1    = (const float*)d_in[12];
    const float* W2    = (const float*)d_in[13];
    const float* b2    = (const float*)d_in[14];

    float* x = (float*)d_out;  // activation buffer lives in d_out

    // Workspace layout (lifetimes: qkv and h are disjoint -> share a region)
    char* ws = (char*)d_ws;
    int*   pos = (int*)ws;                                    // 32 KB (rounded to 64 KB)
    float* qkv = (float*)(ws + 65536);                        // 8192*1536*4 = 50.3 MB
    float* hbuf = qkv;                                        // 8192*2048*4 = 67.1 MB (overlaps qkv)
    float* obuf = (float*)(ws + 65536 + 67108864);            // 16.8 MB
    float* tmp  = obuf + (size_t)ROWS * DMODEL;               // 16.8 MB

    // 1) positions + positional embedding
    pos_scan_kernel<<<BATCH, SEQ, 0, stream>>>(mask, pos);
    add_pos_kernel<<<ROWS, 128, 0, stream>>>(x_in, pos, x);

    for (int l = 0; l < LAYERS; ++l) {
        const float* wqkv_l = Wqkv + (size_t)l * DMODEL * 3 * DMODEL;
        const float* wfc_l  = Wfc + (size_t)l * DMODEL * DMODEL;
        const float* bfc_l  = bfc + (size_t)l * DMODEL;
        const float* w1_l   = W1 + (size_t)l * DMODEL * FFDIM;
        const float* b1_l   = b1 + (size_t)l * FFDIM;
        const float* w2_l   = W2 + (size_t)l * FFDIM * DMODEL;
        const float* b2_l   = b2 + (size_t)l * DMODEL;

        // qkv = x @ Wqkv
        gemm_kernel<false, false><<<dim3(3 * DMODEL / 128, ROWS / 128), 256, 0, stream>>>(
            x, wqkv_l, nullptr, qkv, ROWS, 3 * DMODEL, DMODEL);
        // attention -> obuf
        attn_kernel<<<dim3(4, BATCH * NHEAD), 256, 0, stream>>>(qkv, mask, obuf);
        // tmp = obuf @ Wfc + bfc
        gemm_kernel<true, false><<<dim3(DMODEL / 128, ROWS / 128), 256, 0, stream>>>(
            obuf, wfc_l, bfc_l, tmp, ROWS, DMODEL, DMODEL);
        // x = LN(tmp + x)
        ln_kernel<<<ROWS, 64, 0, stream>>>(tmp, x, ln1_g + (size_t)l * DMODEL,
                                           ln1_b + (size_t)l * DMODEL);
        // h = relu(x @ W1 + b1)
        gemm_kernel<true, true><<<dim3(FFDIM / 128, ROWS / 128), 256, 0, stream>>>(
            x, w1_l, b1_l, hbuf, ROWS, FFDIM, DMODEL);
        // tmp = h @ W2 + b2
        gemm_kernel<true, false><<<dim3(DMODEL / 128, ROWS / 128), 256, 0, stream>>>(
            hbuf, w2_l, b2_l, tmp, ROWS, DMODEL, FFDIM);
        // x = LN(tmp + x)
        ln_kernel<<<ROWS, 64, 0, stream>>>(tmp, x, ln2_g + (size_t)l * DMODEL,
                                           ln2_b + (size_t)l * DMODEL);
    }
}

// Round 2
// 5824.528 us; speedup vs baseline: 1.6197x; 1.6197x over previous
//
#include <hip/hip_runtime.h>
#include <math.h>

// Problem constants
#define LAYERS 6
#define DMODEL 512
#define NHEAD 8
#define DHEAD 64
#define FFDIM 2048
#define BATCH 8
#define SEQ 1024
#define ROWS (BATCH * SEQ)   // 8192
#define EPS 1e-5f

typedef __attribute__((ext_vector_type(8))) short bf16x8;
typedef __attribute__((ext_vector_type(4))) float f32x4;

__device__ inline short f2bf(float f) {
    union { float f; unsigned u; } v; v.f = f;
    unsigned r = (v.u + 0x7FFFu + ((v.u >> 16) & 1u)) >> 16;
    return (short)r;
}

__device__ inline bf16x8 pack8(float4 a, float4 b) {
    bf16x8 r;
    r[0] = f2bf(a.x); r[1] = f2bf(a.y); r[2] = f2bf(a.z); r[3] = f2bf(a.w);
    r[4] = f2bf(b.x); r[5] = f2bf(b.y); r[6] = f2bf(b.z); r[7] = f2bf(b.w);
    return r;
}

// ---------------------------------------------------------------------------
// Positional scan: positions = cumsum(mask!=0) * (mask!=0), per batch row
// ---------------------------------------------------------------------------
__global__ void pos_scan_kernel(const int* __restrict__ mask, int* __restrict__ pos) {
    __shared__ int sm[SEQ];
    int b = blockIdx.x;
    int t = threadIdx.x;
    int v = (mask[b * SEQ + t] != 0) ? 1 : 0;
    sm[t] = v;
    __syncthreads();
    for (int off = 1; off < SEQ; off <<= 1) {
        int add = (t >= off) ? sm[t - off] : 0;
        __syncthreads();
        sm[t] += add;
        __syncthreads();
    }
    pos[b * SEQ + t] = sm[t] * v;
}

// ---------------------------------------------------------------------------
// x = x_in + sin_pos_table[pos]
// ---------------------------------------------------------------------------
__global__ void add_pos_kernel(const float* __restrict__ xin, const int* __restrict__ pos,
                               float* __restrict__ xout) {
    int bs = blockIdx.x;
    int t = threadIdx.x;
    int p = pos[bs];
    int d0 = t * 4;
    const float C = -logf(10000.0f) * (1.0f / 255.0f);  // half-1 = 255
    float4 xv = *(const float4*)(xin + (size_t)bs * DMODEL + d0);
    float e[4];
#pragma unroll
    for (int j = 0; j < 4; ++j) {
        int d = d0 + j;
        if (p == 0) {
            e[j] = 0.0f;
        } else {
            int dd = (d < 256) ? d : d - 256;
            float freq = expf((float)dd * C);
            float ang = (float)p * freq;
            e[j] = (d < 256) ? sinf(ang) : cosf(ang);
        }
    }
    float4 ov;
    ov.x = xv.x + e[0]; ov.y = xv.y + e[1]; ov.z = xv.z + e[2]; ov.w = xv.w + e[3];
    *(float4*)(xout + (size_t)bs * DMODEL + d0) = ov;
}

// ---------------------------------------------------------------------------
// fp32 tiled GEMM: C[M,N] = A[M,K] @ B[K,N] (+bias) (+relu)
// 128x128 tile, BK=8, 256 threads, 8x8 micro-tile per thread
// ---------------------------------------------------------------------------
template <bool BIAS, bool RELU>
__global__ __launch_bounds__(256) void gemm_kernel(const float* __restrict__ A,
                                                   const float* __restrict__ B,
                                                   const float* __restrict__ bias,
                                                   float* __restrict__ C,
                                                   int M, int N, int K) {
    __shared__ float As[8][132];
    __shared__ float Bs[8][132];
    const int t = threadIdx.x;
    const int n0 = blockIdx.x * 128;
    const int m0 = blockIdx.y * 128;
    const int tx = t & 15;
    const int ty = t >> 4;

    const int am = t >> 1;
    const int ak = (t & 1) * 4;
    const int bk = t >> 5;
    const int bn = (t & 31) * 4;

    const float* Aptr = A + (size_t)(m0 + am) * K + ak;
    const float* Bptr = B + (size_t)bk * N + n0 + bn;

    float acc[8][8] = {};

    for (int k0 = 0; k0 < K; k0 += 8) {
        float4 a4 = *(const float4*)(Aptr + k0);
        float4 b4 = *(const float4*)(Bptr + (size_t)k0 * N);
        As[ak + 0][am] = a4.x;
        As[ak + 1][am] = a4.y;
        As[ak + 2][am] = a4.z;
        As[ak + 3][am] = a4.w;
        *(float4*)&Bs[bk][bn] = b4;
        __syncthreads();
#pragma unroll
        for (int k = 0; k < 8; ++k) {
            float4 a0 = *(const float4*)&As[k][ty * 4];
            float4 a1 = *(const float4*)&As[k][ty * 4 + 64];
            float4 b0 = *(const float4*)&Bs[k][tx * 4];
            float4 b1 = *(const float4*)&Bs[k][tx * 4 + 64];
            float av[8] = {a0.x, a0.y, a0.z, a0.w, a1.x, a1.y, a1.z, a1.w};
            float bv[8] = {b0.x, b0.y, b0.z, b0.w, b1.x, b1.y, b1.z, b1.w};
#pragma unroll
            for (int i = 0; i < 8; ++i)
#pragma unroll
                for (int j = 0; j < 8; ++j) acc[i][j] += av[i] * bv[j];
        }
        __syncthreads();
    }

#pragma unroll
    for (int ih = 0; ih < 2; ++ih)
#pragma unroll
        for (int ii = 0; ii < 4; ++ii) {
            int m = m0 + ih * 64 + ty * 4 + ii;
#pragma unroll
            for (int jh = 0; jh < 2; ++jh) {
                int n = n0 + jh * 64 + tx * 4;
                float4 v;
                v.x = acc[ih * 4 + ii][jh * 4 + 0];
                v.y = acc[ih * 4 + ii][jh * 4 + 1];
                v.z = acc[ih * 4 + ii][jh * 4 + 2];
                v.w = acc[ih * 4 + ii][jh * 4 + 3];
                if (BIAS) {
                    v.x += bias[n]; v.y += bias[n + 1]; v.z += bias[n + 2]; v.w += bias[n + 3];
                }
                if (RELU) {
                    v.x = fmaxf(v.x, 0.f); v.y = fmaxf(v.y, 0.f);
                    v.z = fmaxf(v.z, 0.f); v.w = fmaxf(v.w, 0.f);
                }
                *(float4*)(C + (size_t)m * N + n) = v;
            }
        }
}

// ---------------------------------------------------------------------------
// bf16-MFMA flash attention.
// Grid: (S/128 q-tiles, B*H). 256 threads = 4 waves; each wave owns 32 q-rows
// (2 MFMA m-tiles of 16). Per 64-key tile: K,V^T staged in LDS (bf16, stride
// 72 to balance banks), S = Q@K^T via mfma_f32_16x16x32_bf16, branch-free
// online softmax (16-lane xor-shuffle row reduce), P -> A-layout via per-wave
// LDS round-trip, O += P@V in fp32 C-layout regs.
// C/D layout: col=lane&15, row=quad*4+reg.  A: m=lane&15, k=quad*8+j.
// B: n=lane&15, k=quad*8+j.
// qkv rows: [B*S, 3D] (q|k|v), head h at cols h*64..h*64+63.
// o: [B*S, D] head-major (== [B,S,H,dh] flattened).
// ---------------------------------------------------------------------------
#define QTILE 128
__global__ __launch_bounds__(256) void attn_mfma_kernel(const float* __restrict__ qkv,
                                                        const int* __restrict__ mask,
                                                        float* __restrict__ o) {
    __shared__ __attribute__((aligned(16))) short Ks[64][72];   // Ks[key][d]
    __shared__ __attribute__((aligned(16))) short Vt[64][72];   // Vt[d][key]
    __shared__ __attribute__((aligned(16))) short Ps[4][16][72]; // per-wave P[m][key]
    __shared__ int Ms[64];

    const int qt = blockIdx.x;          // 0..7
    const int bh = blockIdx.y;          // 0..63
    const int b = bh >> 3, h = bh & 7;
    const int tid = threadIdx.x;
    const int w = tid >> 6;
    const int lane = tid & 63;
    const int quad = lane >> 4;
    const int lr = lane & 15;

    // Q fragments, persistent: qf[mtile][kchunk]
    bf16x8 qf[2][2];
#pragma unroll
    for (int mt = 0; mt < 2; ++mt)
#pragma unroll
        for (int c = 0; c < 2; ++c) {
            const float* qp = qkv + (size_t)(b * SEQ + qt * QTILE + w * 32 + mt * 16 + lr) * (3 * DMODEL)
                              + h * DHEAD + c * 32 + quad * 8;
            qf[mt][c] = pack8(*(const float4*)qp, *(const float4*)(qp + 4));
        }

    f32x4 Oacc[2][4];
    float m_run[2][4], l_run[2][4];
#pragma unroll
    for (int mt = 0; mt < 2; ++mt)
#pragma unroll
        for (int t2 = 0; t2 < 4; ++t2) { Oacc[mt][t2][0] = 0.f; Oacc[mt][t2][1] = 0.f; Oacc[mt][t2][2] = 0.f; Oacc[mt][t2][3] = 0.f; }
#pragma unroll
    for (int mt = 0; mt < 2; ++mt)
#pragma unroll
        for (int r = 0; r < 4; ++r) { m_run[mt][r] = -1e30f; l_run[mt][r] = 0.f; }

    for (int kt = 0; kt < 16; ++kt) {
        __syncthreads();
        // ---- stage K tile (row-major bf16) and V tile (transposed bf16) ----
        {
            const int key = tid >> 2;
            const int d0 = (tid & 3) * 16;
            const float* kp = qkv + (size_t)(b * SEQ + kt * 64 + key) * (3 * DMODEL)
                              + DMODEL + h * DHEAD + d0;
            float4 k0 = *(const float4*)(kp);
            float4 k1 = *(const float4*)(kp + 4);
            float4 k2 = *(const float4*)(kp + 8);
            float4 k3 = *(const float4*)(kp + 12);
            *(bf16x8*)&Ks[key][d0]     = pack8(k0, k1);
            *(bf16x8*)&Ks[key][d0 + 8] = pack8(k2, k3);
            const float* vp = kp + DMODEL;
            float4 v0 = *(const float4*)(vp);
            float4 v1 = *(const float4*)(vp + 4);
            float4 v2 = *(const float4*)(vp + 8);
            float4 v3 = *(const float4*)(vp + 12);
            float vv[16] = {v0.x, v0.y, v0.z, v0.w, v1.x, v1.y, v1.z, v1.w,
                            v2.x, v2.y, v2.z, v2.w, v3.x, v3.y, v3.z, v3.w};
#pragma unroll
            for (int i = 0; i < 16; ++i) Vt[d0 + i][key] = f2bf(vv[i]);
        }
        if (tid < 64) Ms[tid] = mask[b * SEQ + kt * 64 + tid];
        __syncthreads();

        for (int mt = 0; mt < 2; ++mt) {
            // ---- S = Q @ K^T : 4 col-tiles of 16 keys ----
            f32x4 S[4];
#pragma unroll
            for (int t = 0; t < 4; ++t) { S[t][0] = 0.f; S[t][1] = 0.f; S[t][2] = 0.f; S[t][3] = 0.f; }
#pragma unroll
            for (int c = 0; c < 2; ++c)
#pragma unroll
                for (int t = 0; t < 4; ++t) {
                    bf16x8 kb = *(const bf16x8*)&Ks[lr + 16 * t][quad * 8 + 32 * c];
                    S[t] = __builtin_amdgcn_mfma_f32_16x16x32_bf16(qf[mt][c], kb, S[t], 0, 0, 0);
                }
            // ---- mask ----
#pragma unroll
            for (int t = 0; t < 4; ++t)
                if (Ms[lr + 16 * t] == 0) { S[t][0] = -1e30f; S[t][1] = -1e30f; S[t][2] = -1e30f; S[t][3] = -1e30f; }
            // ---- online softmax (row r = quad*4+reg) ----
            float rmax[4];
#pragma unroll
            for (int r = 0; r < 4; ++r)
                rmax[r] = fmaxf(fmaxf(S[0][r], S[1][r]), fmaxf(S[2][r], S[3][r]));
#pragma unroll
            for (int off = 1; off < 16; off <<= 1)
#pragma unroll
                for (int r = 0; r < 4; ++r)
                    rmax[r] = fmaxf(rmax[r], __shfl_xor(rmax[r], off));
            float alpha[4], rsum[4];
#pragma unroll
            for (int r = 0; r < 4; ++r) {
                float mn = fmaxf(m_run[mt][r], rmax[r]);
                alpha[r] = __expf(m_run[mt][r] - mn);
                m_run[mt][r] = mn;
                rsum[r] = 0.f;
            }
#pragma unroll
            for (int t = 0; t < 4; ++t)
#pragma unroll
                for (int r = 0; r < 4; ++r) {
                    float p = __expf(S[t][r] - m_run[mt][r]);
                    S[t][r] = p;
                    rsum[r] += p;
                }
#pragma unroll
            for (int off = 1; off < 16; off <<= 1)
#pragma unroll
                for (int r = 0; r < 4; ++r)
                    rsum[r] += __shfl_xor(rsum[r], off);
#pragma unroll
            for (int r = 0; r < 4; ++r)
                l_run[mt][r] = l_run[mt][r] * alpha[r] + rsum[r];
            // ---- P (C-layout) -> LDS -> A-layout ----
#pragma unroll
            for (int t = 0; t < 4; ++t)
#pragma unroll
                for (int r = 0; r < 4; ++r)
                    Ps[w][quad * 4 + r][lr + 16 * t] = f2bf(S[t][r]);
            // wave-internal write->read: compiler inserts lgkmcnt wait
            bf16x8 pa0 = *(const bf16x8*)&Ps[w][lr][quad * 8];
            bf16x8 pa1 = *(const bf16x8*)&Ps[w][lr][quad * 8 + 32];
            // ---- rescale O, accumulate P@V ----
#pragma unroll
            for (int t2 = 0; t2 < 4; ++t2) {
#pragma unroll
                for (int r = 0; r < 4; ++r) Oacc[mt][t2][r] *= alpha[r];
                bf16x8 vb0 = *(const bf16x8*)&Vt[lr + 16 * t2][quad * 8];
                bf16x8 vb1 = *(const bf16x8*)&Vt[lr + 16 * t2][quad * 8 + 32];
                Oacc[mt][t2] = __builtin_amdgcn_mfma_f32_16x16x32_bf16(pa0, vb0, Oacc[mt][t2], 0, 0, 0);
                Oacc[mt][t2] = __builtin_amdgcn_mfma_f32_16x16x32_bf16(pa1, vb1, Oacc[mt][t2], 0, 0, 0);
            }
        }
    }

    // ---- epilogue: O / l, store (C-layout: row=quad*4+r, col=lr+16*t2) ----
#pragma unroll
    for (int mt = 0; mt < 2; ++mt) {
        float inv[4];
#pragma unroll
        for (int r = 0; r < 4; ++r) inv[r] = 1.f / l_run[mt][r];
#pragma unroll
        for (int t2 = 0; t2 < 4; ++t2)
#pragma unroll
            for (int r = 0; r < 4; ++r) {
                int row = qt * QTILE + w * 32 + mt * 16 + quad * 4 + r;
                o[(size_t)(b * SEQ + row) * DMODEL + h * DHEAD + 16 * t2 + lr] = Oacc[mt][t2][r] * inv[r];
            }
    }
}

// ---------------------------------------------------------------------------
// x = LayerNorm(tmp + x) * g + b   (in-place on x). One wave per row.
// ---------------------------------------------------------------------------
__global__ __launch_bounds__(64) void ln_kernel(const float* __restrict__ tmp,
                                                float* __restrict__ x,
                                                const float* __restrict__ g,
                                                const float* __restrict__ bta) {
    const int row = blockIdx.x;
    const int t = threadIdx.x;
    const size_t base = (size_t)row * DMODEL + t * 8;
    float4 x0 = *(const float4*)(x + base);
    float4 x1 = *(const float4*)(x + base + 4);
    float4 t0 = *(const float4*)(tmp + base);
    float4 t1 = *(const float4*)(tmp + base + 4);
    float v[8];
    v[0] = x0.x + t0.x; v[1] = x0.y + t0.y; v[2] = x0.z + t0.z; v[3] = x0.w + t0.w;
    v[4] = x1.x + t1.x; v[5] = x1.y + t1.y; v[6] = x1.z + t1.z; v[7] = x1.w + t1.w;
    float s = 0.f, sq = 0.f;
#pragma unroll
    for (int i = 0; i < 8; ++i) { s += v[i]; sq += v[i] * v[i]; }
#pragma unroll
    for (int off = 1; off < 64; off <<= 1) {
        s += __shfl_xor(s, off);
        sq += __shfl_xor(sq, off);
    }
    float mu = s * (1.0f / DMODEL);
    float var = sq * (1.0f / DMODEL) - mu * mu;
    float r = rsqrtf(var + EPS);
    float4 g0 = *(const float4*)(g + t * 8);
    float4 g1 = *(const float4*)(g + t * 8 + 4);
    float4 b0 = *(const float4*)(bta + t * 8);
    float4 b1 = *(const float4*)(bta + t * 8 + 4);
    float4 o0, o1;
    o0.x = (v[0] - mu) * r * g0.x + b0.x;
    o0.y = (v[1] - mu) * r * g0.y + b0.y;
    o0.z = (v[2] - mu) * r * g0.z + b0.z;
    o0.w = (v[3] - mu) * r * g0.w + b0.w;
    o1.x = (v[4] - mu) * r * g1.x + b1.x;
    o1.y = (v[5] - mu) * r * g1.y + b1.y;
    o1.z = (v[6] - mu) * r * g1.z + b1.z;
    o1.w = (v[7] - mu) * r * g1.w + b1.w;
    *(float4*)(x + base) = o0;
    *(float4*)(x + base + 4) = o1;
}

// ---------------------------------------------------------------------------
extern "C" void kernel_launch(void* const* d_in, const int* in_sizes, int n_in,
                              void* d_out, int out_size, void* d_ws, size_t ws_size,
                              hipStream_t stream) {
    const float* x_in  = (const float*)d_in[0];
    const int*   mask  = (const int*)d_in[3];
    const float* Wqkv  = (const float*)d_in[4];
    const float* Wfc   = (const float*)d_in[5];
    const float* bfc   = (const float*)d_in[6];
    const float* ln1_g = (const float*)d_in[7];
    const float* ln1_b = (const float*)d_in[8];
    const float* ln2_g = (const float*)d_in[9];
    const float* ln2_b = (const float*)d_in[10];
    const float* W1    = (const float*)d_in[11];
    const float* b1    = (const float*)d_in[12];
    const float* W2    = (const float*)d_in[13];
    const float* b2    = (const float*)d_in[14];

    float* x = (float*)d_out;  // activation buffer lives in d_out

    char* ws = (char*)d_ws;
    int*   pos = (int*)ws;                                    // 64 KB slot
    float* qkv = (float*)(ws + 65536);                        // 50.3 MB
    float* hbuf = qkv;                                        // 67.1 MB (overlaps qkv; disjoint lifetime)
    float* obuf = (float*)(ws + 65536 + 67108864);            // 16.8 MB
    float* tmp  = obuf + (size_t)ROWS * DMODEL;               // 16.8 MB

    pos_scan_kernel<<<BATCH, SEQ, 0, stream>>>(mask, pos);
    add_pos_kernel<<<ROWS, 128, 0, stream>>>(x_in, pos, x);

    for (int l = 0; l < LAYERS; ++l) {
        const float* wqkv_l = Wqkv + (size_t)l * DMODEL * 3 * DMODEL;
        const float* wfc_l  = Wfc + (size_t)l * DMODEL * DMODEL;
        const float* bfc_l  = bfc + (size_t)l * DMODEL;
        const float* w1_l   = W1 + (size_t)l * DMODEL * FFDIM;
        const float* b1_l   = b1 + (size_t)l * FFDIM;
        const float* w2_l   = W2 + (size_t)l * FFDIM * DMODEL;
        const float* b2_l   = b2 + (size_t)l * DMODEL;

        gemm_kernel<false, false><<<dim3(3 * DMODEL / 128, ROWS / 128), 256, 0, stream>>>(
            x, wqkv_l, nullptr, qkv, ROWS, 3 * DMODEL, DMODEL);
        attn_mfma_kernel<<<dim3(SEQ / QTILE, BATCH * NHEAD), 256, 0, stream>>>(qkv, mask, obuf);
        gemm_kernel<true, false><<<dim3(DMODEL / 128, ROWS / 128), 256, 0, stream>>>(
            obuf, wfc_l, bfc_l, tmp, ROWS, DMODEL, DMODEL);
        ln_kernel<<<ROWS, 64, 0, stream>>>(tmp, x, ln1_g + (size_t)l * DMODEL,
                                           ln1_b + (size_t)l * DMODEL);
        gemm_kernel<true, true><<<dim3(FFDIM / 128, ROWS / 128), 256, 0, stream>>>(
            x, w1_l, b1_l, hbuf, ROWS, FFDIM, DMODEL);
        gemm_kernel<true, false><<<dim3(DMODEL / 128, ROWS / 128), 256, 0, stream>>>(
            hbuf, w2_l, b2_l, tmp, ROWS, DMODEL, FFDIM);
        ln_kernel<<<ROWS, 64, 0, stream>>>(tmp, x, ln2_g + (size_t)l * DMODEL,
                                           ln2_b + (size_t)l * DMODEL);
    }
}

// Round 3
// 1476.894 us; speedup vs baseline: 6.3876x; 3.9438x over previous
//
#include <hip/hip_runtime.h>
#include <math.h>

// Problem constants
#define LAYERS 6
#define DMODEL 512
#define NHEAD 8
#define DHEAD 64
#define FFDIM 2048
#define BATCH 8
#define SEQ 1024
#define ROWS (BATCH * SEQ)   // 8192
#define EPS 1e-5f

typedef __attribute__((ext_vector_type(8))) short bf16x8;
typedef __attribute__((ext_vector_type(4))) float f32x4;

__device__ inline short f2bf(float f) {
    union { float f; unsigned u; } v; v.f = f;
    unsigned r = (v.u + 0x7FFFu + ((v.u >> 16) & 1u)) >> 16;
    return (short)r;
}

__device__ inline bf16x8 pack8(float4 a, float4 b) {
    bf16x8 r;
    r[0] = f2bf(a.x); r[1] = f2bf(a.y); r[2] = f2bf(a.z); r[3] = f2bf(a.w);
    r[4] = f2bf(b.x); r[5] = f2bf(b.y); r[6] = f2bf(b.z); r[7] = f2bf(b.w);
    return r;
}

// async global(bf16,16B) -> LDS staging; data lands at wave-uniform base + lane*16
#define GLOAD_LDS16(g, l)                                                      \
    __builtin_amdgcn_global_load_lds(                                          \
        (__attribute__((address_space(1))) void*)(g),                          \
        (__attribute__((address_space(3))) void*)(l), 16, 0, 0)

// ---------------------------------------------------------------------------
// Weight transpose + fp32->bf16: src [L][K][N] f32 -> dst [L][N][K] bf16
// block (32,8), grid (N/32, K/32, L)
// ---------------------------------------------------------------------------
__global__ void wtrans_kernel(const float* __restrict__ src, short* __restrict__ dst,
                              int K, int N) {
    __shared__ float t[32][33];
    const size_t mofs = (size_t)blockIdx.z * K * N;
    src += mofs; dst += mofs;
    int n0 = blockIdx.x * 32, k0 = blockIdx.y * 32;
    int tx = threadIdx.x, ty = threadIdx.y;
#pragma unroll
    for (int i = 0; i < 4; ++i)
        t[ty + 8 * i][tx] = src[(size_t)(k0 + ty + 8 * i) * N + n0 + tx];
    __syncthreads();
#pragma unroll
    for (int i = 0; i < 4; ++i)
        dst[(size_t)(n0 + ty + 8 * i) * K + k0 + tx] = f2bf(t[tx][ty + 8 * i]);
}

// ---------------------------------------------------------------------------
// Positional scan: positions = cumsum(mask!=0) * (mask!=0), per batch row
// ---------------------------------------------------------------------------
__global__ void pos_scan_kernel(const int* __restrict__ mask, int* __restrict__ pos) {
    __shared__ int sm[SEQ];
    int b = blockIdx.x;
    int t = threadIdx.x;
    int v = (mask[b * SEQ + t] != 0) ? 1 : 0;
    sm[t] = v;
    __syncthreads();
    for (int off = 1; off < SEQ; off <<= 1) {
        int add = (t >= off) ? sm[t - off] : 0;
        __syncthreads();
        sm[t] += add;
        __syncthreads();
    }
    pos[b * SEQ + t] = sm[t] * v;
}

// ---------------------------------------------------------------------------
// x = x_in + sin_pos_table[pos]; writes fp32 master + bf16 copy
// ---------------------------------------------------------------------------
__global__ void add_pos_kernel(const float* __restrict__ xin, const int* __restrict__ pos,
                               float* __restrict__ xout, short* __restrict__ xb) {
    int bs = blockIdx.x;
    int t = threadIdx.x;
    int p = pos[bs];
    int d0 = t * 4;
    const float C = -logf(10000.0f) * (1.0f / 255.0f);  // half-1 = 255
    float4 xv = *(const float4*)(xin + (size_t)bs * DMODEL + d0);
    float e[4];
#pragma unroll
    for (int j = 0; j < 4; ++j) {
        int d = d0 + j;
        if (p == 0) {
            e[j] = 0.0f;
        } else {
            int dd = (d < 256) ? d : d - 256;
            float freq = expf((float)dd * C);
            float ang = (float)p * freq;
            e[j] = (d < 256) ? sinf(ang) : cosf(ang);
        }
    }
    float4 ov;
    ov.x = xv.x + e[0]; ov.y = xv.y + e[1]; ov.z = xv.z + e[2]; ov.w = xv.w + e[3];
    *(float4*)(xout + (size_t)bs * DMODEL + d0) = ov;
    short4 sb;
    sb.x = f2bf(ov.x); sb.y = f2bf(ov.y); sb.z = f2bf(ov.z); sb.w = f2bf(ov.w);
    *(short4*)(xb + (size_t)bs * DMODEL + d0) = sb;
}

// ---------------------------------------------------------------------------
// bf16 MFMA GEMM (m97 structure): C[M,N] = A[M,K] @ BT[N,K]^T (+bias)(+relu)
// A, BT bf16 K-major; C fp32 or bf16. 128x128 tile, BK=32, 256 thr = 4 waves
// (2x2 of 64x64), each wave 4x4 MFMA 16x16x32 tiles. global_load_lds staging.
// ---------------------------------------------------------------------------
template <bool OUTBF16, bool BIAS, bool RELU>
__global__ __launch_bounds__(256) void gemm_bf16_kernel(const short* __restrict__ A,
                                                        const short* __restrict__ BT,
                                                        const float* __restrict__ bias,
                                                        void* __restrict__ Cv,
                                                        int M, int N, int K) {
    __shared__ __attribute__((aligned(16))) short Asm[128 * 32];
    __shared__ __attribute__((aligned(16))) short Bsm[128 * 32];
    const int tid = threadIdx.x;
    const int w = tid >> 6;
    const int lane = tid & 63;
    const int quad = lane >> 4;
    const int lr = lane & 15;
    const int m0 = blockIdx.y * 128;
    const int n0 = blockIdx.x * 128;
    const int wm = (w >> 1) * 64;
    const int wn = (w & 1) * 64;

    // staging: 8 segments of 16 rows; wave w owns segs {2w, 2w+1}
    const int segr = lane >> 2;          // row within segment
    const int segk = (lane & 3) * 8;     // k-offset (shorts)
    const int sA0 = w * 2, sA1 = w * 2 + 1;
    const short* gA0 = A + (size_t)(m0 + sA0 * 16 + segr) * K + segk;
    const short* gA1 = A + (size_t)(m0 + sA1 * 16 + segr) * K + segk;
    const short* gB0 = BT + (size_t)(n0 + sA0 * 16 + segr) * K + segk;
    const short* gB1 = BT + (size_t)(n0 + sA1 * 16 + segr) * K + segk;
    short* lA0 = &Asm[sA0 * 512 + lane * 8];
    short* lA1 = &Asm[sA1 * 512 + lane * 8];
    short* lB0 = &Bsm[sA0 * 512 + lane * 8];
    short* lB1 = &Bsm[sA1 * 512 + lane * 8];

    f32x4 acc[4][4];
#pragma unroll
    for (int i = 0; i < 4; ++i)
#pragma unroll
        for (int j = 0; j < 4; ++j) { acc[i][j][0] = 0.f; acc[i][j][1] = 0.f; acc[i][j][2] = 0.f; acc[i][j][3] = 0.f; }

    for (int k0 = 0; k0 < K; k0 += 32) {
        GLOAD_LDS16(gA0 + k0, lA0);
        GLOAD_LDS16(gA1 + k0, lA1);
        GLOAD_LDS16(gB0 + k0, lB0);
        GLOAD_LDS16(gB1 + k0, lB1);
        __syncthreads();  // drains vmcnt(0): LDS tiles complete

        bf16x8 af[4], bfr[4];
#pragma unroll
        for (int mt = 0; mt < 4; ++mt)
            af[mt] = *(const bf16x8*)&Asm[(wm + mt * 16 + lr) * 32 + quad * 8];
#pragma unroll
        for (int nt = 0; nt < 4; ++nt)
            bfr[nt] = *(const bf16x8*)&Bsm[(wn + nt * 16 + lr) * 32 + quad * 8];
#pragma unroll
        for (int mt = 0; mt < 4; ++mt)
#pragma unroll
            for (int nt = 0; nt < 4; ++nt)
                acc[mt][nt] = __builtin_amdgcn_mfma_f32_16x16x32_bf16(af[mt], bfr[nt], acc[mt][nt], 0, 0, 0);
        __syncthreads();  // done reading LDS before next stage
    }

    float bv[4];
    if (BIAS) {
#pragma unroll
        for (int nt = 0; nt < 4; ++nt) bv[nt] = bias[n0 + wn + nt * 16 + lr];
    }
#pragma unroll
    for (int mt = 0; mt < 4; ++mt)
#pragma unroll
        for (int nt = 0; nt < 4; ++nt)
#pragma unroll
            for (int r = 0; r < 4; ++r) {
                float v = acc[mt][nt][r];
                if (BIAS) v += bv[nt];
                if (RELU) v = fmaxf(v, 0.f);
                int row = m0 + wm + mt * 16 + quad * 4 + r;
                int col = n0 + wn + nt * 16 + lr;
                if (OUTBF16)
                    ((short*)Cv)[(size_t)row * N + col] = f2bf(v);
                else
                    ((float*)Cv)[(size_t)row * N + col] = v;
            }
}

// ---------------------------------------------------------------------------
// bf16-MFMA flash attention (qkv input is bf16).
// Grid: (S/128, B*H). 256 thr = 4 waves; wave owns 32 q-rows (2 m-tiles).
// qkv rows: [B*S, 3D] bf16 (q|k|v), head h at cols h*64. o: [B*S,D] bf16.
// ---------------------------------------------------------------------------
#define QTILE 128
__global__ __launch_bounds__(256) void attn_mfma_kernel(const short* __restrict__ qkv,
                                                        const int* __restrict__ mask,
                                                        short* __restrict__ o) {
    __shared__ __attribute__((aligned(16))) short Ks[64][72];    // Ks[key][d]
    __shared__ __attribute__((aligned(16))) short Vt[64][72];    // Vt[d][key]
    __shared__ __attribute__((aligned(16))) short Ps[4][16][72]; // per-wave P[m][key]
    __shared__ int Ms[64];

    const int qt = blockIdx.x;
    const int bh = blockIdx.y;
    const int b = bh >> 3, h = bh & 7;
    const int tid = threadIdx.x;
    const int w = tid >> 6;
    const int lane = tid & 63;
    const int quad = lane >> 4;
    const int lr = lane & 15;

    bf16x8 qf[2][2];
#pragma unroll
    for (int mt = 0; mt < 2; ++mt)
#pragma unroll
        for (int c = 0; c < 2; ++c) {
            const short* qp = qkv + (size_t)(b * SEQ + qt * QTILE + w * 32 + mt * 16 + lr) * (3 * DMODEL)
                              + h * DHEAD + c * 32 + quad * 8;
            qf[mt][c] = *(const bf16x8*)qp;
        }

    f32x4 Oacc[2][4];
    float m_run[2][4], l_run[2][4];
#pragma unroll
    for (int mt = 0; mt < 2; ++mt)
#pragma unroll
        for (int t2 = 0; t2 < 4; ++t2) { Oacc[mt][t2][0] = 0.f; Oacc[mt][t2][1] = 0.f; Oacc[mt][t2][2] = 0.f; Oacc[mt][t2][3] = 0.f; }
#pragma unroll
    for (int mt = 0; mt < 2; ++mt)
#pragma unroll
        for (int r = 0; r < 4; ++r) { m_run[mt][r] = -1e30f; l_run[mt][r] = 0.f; }

    for (int kt = 0; kt < 16; ++kt) {
        __syncthreads();
        {
            const int key = tid >> 2;
            const int d0 = (tid & 3) * 16;
            const short* kp = qkv + (size_t)(b * SEQ + kt * 64 + key) * (3 * DMODEL)
                              + DMODEL + h * DHEAD + d0;
            *(bf16x8*)&Ks[key][d0]     = *(const bf16x8*)(kp);
            *(bf16x8*)&Ks[key][d0 + 8] = *(const bf16x8*)(kp + 8);
            bf16x8 v0 = *(const bf16x8*)(kp + DMODEL);
            bf16x8 v1 = *(const bf16x8*)(kp + DMODEL + 8);
#pragma unroll
            for (int i = 0; i < 8; ++i) Vt[d0 + i][key] = v0[i];
#pragma unroll
            for (int i = 0; i < 8; ++i) Vt[d0 + 8 + i][key] = v1[i];
        }
        if (tid < 64) Ms[tid] = mask[b * SEQ + kt * 64 + tid];
        __syncthreads();

        for (int mt = 0; mt < 2; ++mt) {
            f32x4 S[4];
#pragma unroll
            for (int t = 0; t < 4; ++t) { S[t][0] = 0.f; S[t][1] = 0.f; S[t][2] = 0.f; S[t][3] = 0.f; }
#pragma unroll
            for (int c = 0; c < 2; ++c)
#pragma unroll
                for (int t = 0; t < 4; ++t) {
                    bf16x8 kb = *(const bf16x8*)&Ks[lr + 16 * t][quad * 8 + 32 * c];
                    S[t] = __builtin_amdgcn_mfma_f32_16x16x32_bf16(qf[mt][c], kb, S[t], 0, 0, 0);
                }
#pragma unroll
            for (int t = 0; t < 4; ++t)
                if (Ms[lr + 16 * t] == 0) { S[t][0] = -1e30f; S[t][1] = -1e30f; S[t][2] = -1e30f; S[t][3] = -1e30f; }
            float rmax[4];
#pragma unroll
            for (int r = 0; r < 4; ++r)
                rmax[r] = fmaxf(fmaxf(S[0][r], S[1][r]), fmaxf(S[2][r], S[3][r]));
#pragma unroll
            for (int off = 1; off < 16; off <<= 1)
#pragma unroll
                for (int r = 0; r < 4; ++r)
                    rmax[r] = fmaxf(rmax[r], __shfl_xor(rmax[r], off));
            float alpha[4], rsum[4];
#pragma unroll
            for (int r = 0; r < 4; ++r) {
                float mn = fmaxf(m_run[mt][r], rmax[r]);
                alpha[r] = __expf(m_run[mt][r] - mn);
                m_run[mt][r] = mn;
                rsum[r] = 0.f;
            }
#pragma unroll
            for (int t = 0; t < 4; ++t)
#pragma unroll
                for (int r = 0; r < 4; ++r) {
                    float p = __expf(S[t][r] - m_run[mt][r]);
                    S[t][r] = p;
                    rsum[r] += p;
                }
#pragma unroll
            for (int off = 1; off < 16; off <<= 1)
#pragma unroll
                for (int r = 0; r < 4; ++r)
                    rsum[r] += __shfl_xor(rsum[r], off);
#pragma unroll
            for (int r = 0; r < 4; ++r)
                l_run[mt][r] = l_run[mt][r] * alpha[r] + rsum[r];
#pragma unroll
            for (int t = 0; t < 4; ++t)
#pragma unroll
                for (int r = 0; r < 4; ++r)
                    Ps[w][quad * 4 + r][lr + 16 * t] = f2bf(S[t][r]);
            bf16x8 pa0 = *(const bf16x8*)&Ps[w][lr][quad * 8];
            bf16x8 pa1 = *(const bf16x8*)&Ps[w][lr][quad * 8 + 32];
#pragma unroll
            for (int t2 = 0; t2 < 4; ++t2) {
#pragma unroll
                for (int r = 0; r < 4; ++r) Oacc[mt][t2][r] *= alpha[r];
                bf16x8 vb0 = *(const bf16x8*)&Vt[lr + 16 * t2][quad * 8];
                bf16x8 vb1 = *(const bf16x8*)&Vt[lr + 16 * t2][quad * 8 + 32];
                Oacc[mt][t2] = __builtin_amdgcn_mfma_f32_16x16x32_bf16(pa0, vb0, Oacc[mt][t2], 0, 0, 0);
                Oacc[mt][t2] = __builtin_amdgcn_mfma_f32_16x16x32_bf16(pa1, vb1, Oacc[mt][t2], 0, 0, 0);
            }
        }
    }

#pragma unroll
    for (int mt = 0; mt < 2; ++mt) {
        float inv[4];
#pragma unroll
        for (int r = 0; r < 4; ++r) inv[r] = 1.f / l_run[mt][r];
#pragma unroll
        for (int t2 = 0; t2 < 4; ++t2)
#pragma unroll
            for (int r = 0; r < 4; ++r) {
                int row = qt * QTILE + w * 32 + mt * 16 + quad * 4 + r;
                o[(size_t)(b * SEQ + row) * DMODEL + h * DHEAD + 16 * t2 + lr] = f2bf(Oacc[mt][t2][r] * inv[r]);
            }
    }
}

// ---------------------------------------------------------------------------
// x = LayerNorm(tmp + x) * g + b; writes fp32 master (in-place) + bf16 copy
// ---------------------------------------------------------------------------
__global__ __launch_bounds__(64) void ln_kernel(const float* __restrict__ tmp,
                                                float* __restrict__ x,
                                                short* __restrict__ xb,
                                                const float* __restrict__ g,
                                                const float* __restrict__ bta) {
    const int row = blockIdx.x;
    const int t = threadIdx.x;
    const size_t base = (size_t)row * DMODEL + t * 8;
    float4 x0 = *(const float4*)(x + base);
    float4 x1 = *(const float4*)(x + base + 4);
    float4 t0 = *(const float4*)(tmp + base);
    float4 t1 = *(const float4*)(tmp + base + 4);
    float v[8];
    v[0] = x0.x + t0.x; v[1] = x0.y + t0.y; v[2] = x0.z + t0.z; v[3] = x0.w + t0.w;
    v[4] = x1.x + t1.x; v[5] = x1.y + t1.y; v[6] = x1.z + t1.z; v[7] = x1.w + t1.w;
    float s = 0.f, sq = 0.f;
#pragma unroll
    for (int i = 0; i < 8; ++i) { s += v[i]; sq += v[i] * v[i]; }
#pragma unroll
    for (int off = 1; off < 64; off <<= 1) {
        s += __shfl_xor(s, off);
        sq += __shfl_xor(sq, off);
    }
    float mu = s * (1.0f / DMODEL);
    float var = sq * (1.0f / DMODEL) - mu * mu;
    float r = rsqrtf(var + EPS);
    float4 g0 = *(const float4*)(g + t * 8);
    float4 g1 = *(const float4*)(g + t * 8 + 4);
    float4 b0 = *(const float4*)(bta + t * 8);
    float4 b1 = *(const float4*)(bta + t * 8 + 4);
    float o[8];
    o[0] = (v[0] - mu) * r * g0.x + b0.x;
    o[1] = (v[1] - mu) * r * g0.y + b0.y;
    o[2] = (v[2] - mu) * r * g0.z + b0.z;
    o[3] = (v[3] - mu) * r * g0.w + b0.w;
    o[4] = (v[4] - mu) * r * g1.x + b1.x;
    o[5] = (v[5] - mu) * r * g1.y + b1.y;
    o[6] = (v[6] - mu) * r * g1.z + b1.z;
    o[7] = (v[7] - mu) * r * g1.w + b1.w;
    *(float4*)(x + base) = *(float4*)&o[0];
    *(float4*)(x + base + 4) = *(float4*)&o[4];
    bf16x8 ob;
#pragma unroll
    for (int i = 0; i < 8; ++i) ob[i] = f2bf(o[i]);
    *(bf16x8*)(xb + base) = ob;
}

// ---------------------------------------------------------------------------
extern "C" void kernel_launch(void* const* d_in, const int* in_sizes, int n_in,
                              void* d_out, int out_size, void* d_ws, size_t ws_size,
                              hipStream_t stream) {
    const float* x_in  = (const float*)d_in[0];
    const int*   mask  = (const int*)d_in[3];
    const float* Wqkv  = (const float*)d_in[4];
    const float* Wfc   = (const float*)d_in[5];
    const float* bfc   = (const float*)d_in[6];
    const float* ln1_g = (const float*)d_in[7];
    const float* ln1_b = (const float*)d_in[8];
    const float* ln2_g = (const float*)d_in[9];
    const float* ln2_b = (const float*)d_in[10];
    const float* W1    = (const float*)d_in[11];
    const float* b1    = (const float*)d_in[12];
    const float* W2    = (const float*)d_in[13];
    const float* b2    = (const float*)d_in[14];

    float* x = (float*)d_out;  // fp32 activation master lives in d_out

    // Workspace layout (bytes). hb aliases qkvb+obuf (disjoint lifetimes).
    char* ws = (char*)d_ws;
    size_t ofs = 0;
    int*   pos   = (int*)ws;                 ofs += 65536;
    float* tmp   = (float*)(ws + ofs);       ofs += (size_t)ROWS * DMODEL * 4;   // 16.8 MB
    short* xb    = (short*)(ws + ofs);       ofs += (size_t)ROWS * DMODEL * 2;   // 8.4 MB
    short* qkvb  = (short*)(ws + ofs);
    short* hb    = (short*)(ws + ofs);       // aliases qkvb..obuf (33.6 MB)
    ofs += (size_t)ROWS * 3 * DMODEL * 2;                                        // 25.2 MB
    short* obuf  = (short*)(ws + ofs);       ofs += (size_t)ROWS * DMODEL * 2;   // 8.4 MB
    short* WqkvT = (short*)(ws + ofs);       ofs += (size_t)LAYERS * DMODEL * 3 * DMODEL * 2;
    short* WfcT  = (short*)(ws + ofs);       ofs += (size_t)LAYERS * DMODEL * DMODEL * 2;
    short* W1T   = (short*)(ws + ofs);       ofs += (size_t)LAYERS * DMODEL * FFDIM * 2;
    short* W2T   = (short*)(ws + ofs);       ofs += (size_t)LAYERS * FFDIM * DMODEL * 2;

    // Weight transpose+convert (runs every call; ~40 MB of traffic, ~15 us)
    wtrans_kernel<<<dim3(3 * DMODEL / 32, DMODEL / 32, LAYERS), dim3(32, 8), 0, stream>>>(
        Wqkv, WqkvT, DMODEL, 3 * DMODEL);
    wtrans_kernel<<<dim3(DMODEL / 32, DMODEL / 32, LAYERS), dim3(32, 8), 0, stream>>>(
        Wfc, WfcT, DMODEL, DMODEL);
    wtrans_kernel<<<dim3(FFDIM / 32, DMODEL / 32, LAYERS), dim3(32, 8), 0, stream>>>(
        W1, W1T, DMODEL, FFDIM);
    wtrans_kernel<<<dim3(DMODEL / 32, FFDIM / 32, LAYERS), dim3(32, 8), 0, stream>>>(
        W2, W2T, FFDIM, DMODEL);

    pos_scan_kernel<<<BATCH, SEQ, 0, stream>>>(mask, pos);
    add_pos_kernel<<<ROWS, 128, 0, stream>>>(x_in, pos, x, xb);

    for (int l = 0; l < LAYERS; ++l) {
        const short* wqkvT_l = WqkvT + (size_t)l * DMODEL * 3 * DMODEL;
        const short* wfcT_l  = WfcT + (size_t)l * DMODEL * DMODEL;
        const short* w1T_l   = W1T + (size_t)l * DMODEL * FFDIM;
        const short* w2T_l   = W2T + (size_t)l * FFDIM * DMODEL;
        const float* bfc_l   = bfc + (size_t)l * DMODEL;
        const float* b1_l    = b1 + (size_t)l * FFDIM;
        const float* b2_l    = b2 + (size_t)l * DMODEL;

        // qkv = x @ Wqkv  (bf16 out)
        gemm_bf16_kernel<true, false, false><<<dim3(3 * DMODEL / 128, ROWS / 128), 256, 0, stream>>>(
            xb, wqkvT_l, nullptr, qkvb, ROWS, 3 * DMODEL, DMODEL);
        // attention -> obuf (bf16)
        attn_mfma_kernel<<<dim3(SEQ / QTILE, BATCH * NHEAD), 256, 0, stream>>>(qkvb, mask, obuf);
        // tmp = obuf @ Wfc + bfc  (fp32 out)
        gemm_bf16_kernel<false, true, false><<<dim3(DMODEL / 128, ROWS / 128), 256, 0, stream>>>(
            obuf, wfcT_l, bfc_l, tmp, ROWS, DMODEL, DMODEL);
        // x = LN(tmp + x)
        ln_kernel<<<ROWS, 64, 0, stream>>>(tmp, x, xb, ln1_g + (size_t)l * DMODEL,
                                           ln1_b + (size_t)l * DMODEL);
        // h = relu(x @ W1 + b1)  (bf16 out)
        gemm_bf16_kernel<true, true, true><<<dim3(FFDIM / 128, ROWS / 128), 256, 0, stream>>>(
            xb, w1T_l, b1_l, hb, ROWS, FFDIM, DMODEL);
        // tmp = h @ W2 + b2  (fp32 out)
        gemm_bf16_kernel<false, true, false><<<dim3(DMODEL / 128, ROWS / 128), 256, 0, stream>>>(
            hb, w2T_l, b2_l, tmp, ROWS, DMODEL, FFDIM);
        // x = LN(tmp + x)
        ln_kernel<<<ROWS, 64, 0, stream>>>(tmp, x, xb, ln2_g + (size_t)l * DMODEL,
                                           ln2_b + (size_t)l * DMODEL);
    }
}

// Round 4
// 1152.925 us; speedup vs baseline: 8.1826x; 1.2810x over previous
//
#include <hip/hip_runtime.h>
#include <math.h>

// Problem constants
#define LAYERS 6
#define DMODEL 512
#define NHEAD 8
#define DHEAD 64
#define FFDIM 2048
#define BATCH 8
#define SEQ 1024
#define ROWS (BATCH * SEQ)   // 8192
#define EPS 1e-5f

typedef __attribute__((ext_vector_type(8))) short bf16x8;
typedef __attribute__((ext_vector_type(4))) float f32x4;

__device__ inline short f2bf(float f) {
    union { float f; unsigned u; } v; v.f = f;
    unsigned r = (v.u + 0x7FFFu + ((v.u >> 16) & 1u)) >> 16;
    return (short)r;
}

// async global(bf16,16B) -> LDS staging; data lands at wave-uniform base + lane*16
#define GLOAD_LDS16(g, l)                                                      \
    __builtin_amdgcn_global_load_lds(                                          \
        (__attribute__((address_space(1))) void*)(g),                          \
        (__attribute__((address_space(3))) void*)(l), 16, 0, 0)

// ---------------------------------------------------------------------------
// Weight transpose + fp32->bf16: src [L][K][N] f32 -> dst [L][N][K] bf16
// ---------------------------------------------------------------------------
__global__ void wtrans_kernel(const float* __restrict__ src, short* __restrict__ dst,
                              int K, int N) {
    __shared__ float t[32][33];
    const size_t mofs = (size_t)blockIdx.z * K * N;
    src += mofs; dst += mofs;
    int n0 = blockIdx.x * 32, k0 = blockIdx.y * 32;
    int tx = threadIdx.x, ty = threadIdx.y;
#pragma unroll
    for (int i = 0; i < 4; ++i)
        t[ty + 8 * i][tx] = src[(size_t)(k0 + ty + 8 * i) * N + n0 + tx];
    __syncthreads();
#pragma unroll
    for (int i = 0; i < 4; ++i)
        dst[(size_t)(n0 + ty + 8 * i) * K + k0 + tx] = f2bf(t[tx][ty + 8 * i]);
}

// ---------------------------------------------------------------------------
// Positional scan
// ---------------------------------------------------------------------------
__global__ void pos_scan_kernel(const int* __restrict__ mask, int* __restrict__ pos) {
    __shared__ int sm[SEQ];
    int b = blockIdx.x;
    int t = threadIdx.x;
    int v = (mask[b * SEQ + t] != 0) ? 1 : 0;
    sm[t] = v;
    __syncthreads();
    for (int off = 1; off < SEQ; off <<= 1) {
        int add = (t >= off) ? sm[t - off] : 0;
        __syncthreads();
        sm[t] += add;
        __syncthreads();
    }
    pos[b * SEQ + t] = sm[t] * v;
}

// ---------------------------------------------------------------------------
// x = x_in + sin_pos_table[pos]; writes fp32 master + bf16 copy
// ---------------------------------------------------------------------------
__global__ void add_pos_kernel(const float* __restrict__ xin, const int* __restrict__ pos,
                               float* __restrict__ xout, short* __restrict__ xb) {
    int bs = blockIdx.x;
    int t = threadIdx.x;
    int p = pos[bs];
    int d0 = t * 4;
    const float C = -logf(10000.0f) * (1.0f / 255.0f);  // half-1 = 255
    float4 xv = *(const float4*)(xin + (size_t)bs * DMODEL + d0);
    float e[4];
#pragma unroll
    for (int j = 0; j < 4; ++j) {
        int d = d0 + j;
        if (p == 0) {
            e[j] = 0.0f;
        } else {
            int dd = (d < 256) ? d : d - 256;
            float freq = expf((float)dd * C);
            float ang = (float)p * freq;
            e[j] = (d < 256) ? sinf(ang) : cosf(ang);
        }
    }
    float4 ov;
    ov.x = xv.x + e[0]; ov.y = xv.y + e[1]; ov.z = xv.z + e[2]; ov.w = xv.w + e[3];
    *(float4*)(xout + (size_t)bs * DMODEL + d0) = ov;
    short4 sb;
    sb.x = f2bf(ov.x); sb.y = f2bf(ov.y); sb.z = f2bf(ov.z); sb.w = f2bf(ov.w);
    *(short4*)(xb + (size_t)bs * DMODEL + d0) = sb;
}

// ---------------------------------------------------------------------------
// bf16 MFMA GEMM, single-barrier double-buffered K-loop.
// C[M,N] = A[M,K] @ BT[N,K]^T (+bias)(+relu). 128x128 tile, BK=32, 256 thr.
// ---------------------------------------------------------------------------
template <bool OUTBF16, bool BIAS, bool RELU>
__global__ __launch_bounds__(256) void gemm_bf16_kernel(const short* __restrict__ A,
                                                        const short* __restrict__ BT,
                                                        const float* __restrict__ bias,
                                                        void* __restrict__ Cv,
                                                        int M, int N, int K) {
    __shared__ __attribute__((aligned(16))) short Asm[2][128 * 32];
    __shared__ __attribute__((aligned(16))) short Bsm[2][128 * 32];
    const int tid = threadIdx.x;
    const int w = tid >> 6;
    const int lane = tid & 63;
    const int quad = lane >> 4;
    const int lr = lane & 15;
    const int m0 = blockIdx.y * 128;
    const int n0 = blockIdx.x * 128;
    const int wm = (w >> 1) * 64;
    const int wn = (w & 1) * 64;

    // staging: 8 segments of 16 rows; wave w owns segs {2w, 2w+1}
    const int segr = lane >> 2;
    const int segk = (lane & 3) * 8;
    const int sA0 = w * 2, sA1 = w * 2 + 1;
    const short* gA0 = A + (size_t)(m0 + sA0 * 16 + segr) * K + segk;
    const short* gA1 = A + (size_t)(m0 + sA1 * 16 + segr) * K + segk;
    const short* gB0 = BT + (size_t)(n0 + sA0 * 16 + segr) * K + segk;
    const short* gB1 = BT + (size_t)(n0 + sA1 * 16 + segr) * K + segk;
    const int lofs0 = sA0 * 512 + lane * 8;
    const int lofs1 = sA1 * 512 + lane * 8;

    f32x4 acc[4][4];
#pragma unroll
    for (int i = 0; i < 4; ++i)
#pragma unroll
        for (int j = 0; j < 4; ++j) { acc[i][j][0] = 0.f; acc[i][j][1] = 0.f; acc[i][j][2] = 0.f; acc[i][j][3] = 0.f; }

    // prologue: stage tile 0 into buffer 0
    GLOAD_LDS16(gA0, &Asm[0][lofs0]);
    GLOAD_LDS16(gA1, &Asm[0][lofs1]);
    GLOAD_LDS16(gB0, &Bsm[0][lofs0]);
    GLOAD_LDS16(gB1, &Bsm[0][lofs1]);

    const int nk = K >> 5;
    for (int i = 0; i < nk; ++i) {
        __syncthreads();  // drains vmcnt: buffer (i&1) is staged; prev readers of (i+1)&1 done
        if (i + 1 < nk) {
            const int k1 = (i + 1) * 32;
            const int nb = (i + 1) & 1;
            GLOAD_LDS16(gA0 + k1, &Asm[nb][lofs0]);
            GLOAD_LDS16(gA1 + k1, &Asm[nb][lofs1]);
            GLOAD_LDS16(gB0 + k1, &Bsm[nb][lofs0]);
            GLOAD_LDS16(gB1 + k1, &Bsm[nb][lofs1]);
        }
        const int cur = i & 1;
        bf16x8 af[4], bfr[4];
#pragma unroll
        for (int mt = 0; mt < 4; ++mt)
            af[mt] = *(const bf16x8*)&Asm[cur][(wm + mt * 16 + lr) * 32 + quad * 8];
#pragma unroll
        for (int nt = 0; nt < 4; ++nt)
            bfr[nt] = *(const bf16x8*)&Bsm[cur][(wn + nt * 16 + lr) * 32 + quad * 8];
#pragma unroll
        for (int mt = 0; mt < 4; ++mt)
#pragma unroll
            for (int nt = 0; nt < 4; ++nt)
                acc[mt][nt] = __builtin_amdgcn_mfma_f32_16x16x32_bf16(af[mt], bfr[nt], acc[mt][nt], 0, 0, 0);
    }

    float bv[4];
    if (BIAS) {
#pragma unroll
        for (int nt = 0; nt < 4; ++nt) bv[nt] = bias[n0 + wn + nt * 16 + lr];
    }
#pragma unroll
    for (int mt = 0; mt < 4; ++mt)
#pragma unroll
        for (int nt = 0; nt < 4; ++nt)
#pragma unroll
            for (int r = 0; r < 4; ++r) {
                float v = acc[mt][nt][r];
                if (BIAS) v += bv[nt];
                if (RELU) v = fmaxf(v, 0.f);
                int row = m0 + wm + mt * 16 + quad * 4 + r;
                int col = n0 + wn + nt * 16 + lr;
                if (OUTBF16)
                    ((short*)Cv)[(size_t)row * N + col] = f2bf(v);
                else
                    ((float*)Cv)[(size_t)row * N + col] = v;
            }
}

// ---------------------------------------------------------------------------
// bf16-MFMA flash attention v2: QTILE=256 (512 thr = 8 waves, 32 q-rows each),
// no-rescale softmax (fixed shift 8, exact after normalization), double-
// buffered K/V staging with ONE barrier per tile, conflict-free V-transpose
// (key-pair b32 writes: bank = 4i+kp covers all 32 banks 2-way).
// Masked keys handled by p *= mask (exp of real scores is finite).
// qkv rows: [B*S, 3D] bf16 (q|k|v), head h at cols h*64. o: [B*S,D] bf16.
// ---------------------------------------------------------------------------
#define QTILE 256
__global__ __launch_bounds__(512) void attn_mfma_kernel(const short* __restrict__ qkv,
                                                        const int* __restrict__ mask,
                                                        short* __restrict__ o) {
    __shared__ __attribute__((aligned(16))) short Ks[2][64][72];    // [key][d]
    __shared__ __attribute__((aligned(16))) short Vt[2][64][72];    // [d][key]
    __shared__ __attribute__((aligned(16))) short Ps[8][16][72];    // per-wave P[m][key]
    __shared__ float Msf[2][64];

    const int qt = blockIdx.x;          // 0..3
    const int bh = blockIdx.y;          // 0..63
    const int b = bh >> 3, h = bh & 7;
    const int tid = threadIdx.x;
    const int w = tid >> 6;             // wave 0..7
    const int lane = tid & 63;
    const int quad = lane >> 4;
    const int lr = lane & 15;
    const size_t seqrow = (size_t)b * SEQ;

    // ---- persistent Q fragments ----
    bf16x8 qf[2][2];
#pragma unroll
    for (int mt = 0; mt < 2; ++mt)
#pragma unroll
        for (int c = 0; c < 2; ++c)
            qf[mt][c] = *(const bf16x8*)(qkv +
                (seqrow + qt * QTILE + w * 32 + mt * 16 + lr) * (3 * DMODEL)
                + h * DHEAD + c * 32 + quad * 8);

    // ---- staging roles: waves 0-3 stage K, waves 4-7 stage V (transposed) ----
    const bool isK = (tid < 256);
    const int st = isK ? tid : tid - 256;
    const int kkey = st >> 2;            // K: key row 0..63
    const int kg = (st & 3) * 8;         // K: granule offset (shorts), second at +32
    const int vkp = st & 31;             // V: key pair 0..31
    const int vdg = st >> 5;             // V: d-group 0..7
    const short* gK = qkv + (seqrow + kkey) * (3 * DMODEL) + DMODEL + h * DHEAD + kg;
    const short* gV = qkv + (seqrow + 2 * vkp) * (3 * DMODEL) + 2 * DMODEL + h * DHEAD + vdg * 8;

    bf16x8 r0, r1;
    int mreg = 0;

    // prologue: stage tile 0 -> buffer 0
    {
        if (isK) {
            r0 = *(const bf16x8*)(gK);
            r1 = *(const bf16x8*)(gK + 32);
        } else {
            r0 = *(const bf16x8*)(gV);
            r1 = *(const bf16x8*)(gV + 3 * DMODEL);
        }
        if (tid < 64) mreg = mask[seqrow + tid];
        if (isK) {
            *(bf16x8*)&Ks[0][kkey][kg] = r0;
            *(bf16x8*)&Ks[0][kkey][kg + 32] = r1;
        } else {
#pragma unroll
            for (int i = 0; i < 8; ++i) {
                short2 p; p.x = r0[i]; p.y = r1[i];
                *(short2*)&Vt[0][vdg * 8 + i][vkp * 2] = p;
            }
        }
        if (tid < 64) Msf[0][tid] = mreg ? 1.0f : 0.0f;
    }
    __syncthreads();

    f32x4 Oacc[2][4];
    float rs[2][4];
#pragma unroll
    for (int mt = 0; mt < 2; ++mt)
#pragma unroll
        for (int t2 = 0; t2 < 4; ++t2) { Oacc[mt][t2][0] = 0.f; Oacc[mt][t2][1] = 0.f; Oacc[mt][t2][2] = 0.f; Oacc[mt][t2][3] = 0.f; }
#pragma unroll
    for (int mt = 0; mt < 2; ++mt)
#pragma unroll
        for (int r = 0; r < 4; ++r) rs[mt][r] = 0.f;

    for (int kt = 0; kt < 16; ++kt) {
        const int cur = kt & 1;
        // ---- issue global loads for tile kt+1 (wrap; last iter's result unused) ----
        {
            const size_t ofs = (size_t)((kt + 1) & 15) * 64 * (3 * DMODEL);
            if (isK) {
                r0 = *(const bf16x8*)(gK + ofs);
                r1 = *(const bf16x8*)(gK + ofs + 32);
            } else {
                r0 = *(const bf16x8*)(gV + ofs);
                r1 = *(const bf16x8*)(gV + ofs + 3 * DMODEL);
            }
            if (tid < 64) mreg = mask[seqrow + ((kt + 1) & 15) * 64 + tid];
        }
        // ---- hoisted K/V fragments (shared by both m-tiles) ----
        bf16x8 kf[2][4], vf[2][4];
#pragma unroll
        for (int c = 0; c < 2; ++c)
#pragma unroll
            for (int t = 0; t < 4; ++t) {
                kf[c][t] = *(const bf16x8*)&Ks[cur][lr + 16 * t][quad * 8 + 32 * c];
                vf[c][t] = *(const bf16x8*)&Vt[cur][lr + 16 * t][quad * 8 + 32 * c];
            }
        float mv[4];
#pragma unroll
        for (int t = 0; t < 4; ++t) mv[t] = Msf[cur][lr + 16 * t];

#pragma unroll
        for (int mt = 0; mt < 2; ++mt) {
            f32x4 S[4];
#pragma unroll
            for (int t = 0; t < 4; ++t) { S[t][0] = 0.f; S[t][1] = 0.f; S[t][2] = 0.f; S[t][3] = 0.f; }
#pragma unroll
            for (int c = 0; c < 2; ++c)
#pragma unroll
                for (int t = 0; t < 4; ++t)
                    S[t] = __builtin_amdgcn_mfma_f32_16x16x32_bf16(qf[mt][c], kf[c][t], S[t], 0, 0, 0);
            // softmax numerator (no rescale; shift cancels after normalize)
#pragma unroll
            for (int t = 0; t < 4; ++t)
#pragma unroll
                for (int r = 0; r < 4; ++r) {
                    float p = __expf(S[t][r] - 8.0f) * mv[t];
                    S[t][r] = p;
                    rs[mt][r] += p;
                }
            // P (C-layout) -> LDS -> A-layout (per-wave region, wave-internal RAW)
#pragma unroll
            for (int t = 0; t < 4; ++t)
#pragma unroll
                for (int r = 0; r < 4; ++r)
                    Ps[w][quad * 4 + r][lr + 16 * t] = f2bf(S[t][r]);
            bf16x8 pa0 = *(const bf16x8*)&Ps[w][lr][quad * 8];
            bf16x8 pa1 = *(const bf16x8*)&Ps[w][lr][quad * 8 + 32];
#pragma unroll
            for (int t2 = 0; t2 < 4; ++t2) {
                Oacc[mt][t2] = __builtin_amdgcn_mfma_f32_16x16x32_bf16(pa0, vf[0][t2], Oacc[mt][t2], 0, 0, 0);
                Oacc[mt][t2] = __builtin_amdgcn_mfma_f32_16x16x32_bf16(pa1, vf[1][t2], Oacc[mt][t2], 0, 0, 0);
            }
        }
        // ---- write staged regs -> other buffer (no conflict with current readers) ----
        {
            const int nb = cur ^ 1;
            if (isK) {
                *(bf16x8*)&Ks[nb][kkey][kg] = r0;
                *(bf16x8*)&Ks[nb][kkey][kg + 32] = r1;
            } else {
#pragma unroll
                for (int i = 0; i < 8; ++i) {
                    short2 p; p.x = r0[i]; p.y = r1[i];
                    *(short2*)&Vt[nb][vdg * 8 + i][vkp * 2] = p;
                }
            }
            if (tid < 64) Msf[nb][tid] = mreg ? 1.0f : 0.0f;
        }
        __syncthreads();
    }

    // ---- epilogue: row-sum reduce across 16 lanes, normalize, store ----
#pragma unroll
    for (int mt = 0; mt < 2; ++mt) {
        float inv[4];
#pragma unroll
        for (int r = 0; r < 4; ++r) {
            float v = rs[mt][r];
            v += __shfl_xor(v, 1);
            v += __shfl_xor(v, 2);
            v += __shfl_xor(v, 4);
            v += __shfl_xor(v, 8);
            inv[r] = 1.f / v;
        }
#pragma unroll
        for (int t2 = 0; t2 < 4; ++t2)
#pragma unroll
            for (int r = 0; r < 4; ++r) {
                int row = qt * QTILE + w * 32 + mt * 16 + quad * 4 + r;
                o[(seqrow + row) * DMODEL + h * DHEAD + 16 * t2 + lr] = f2bf(Oacc[mt][t2][r] * inv[r]);
            }
    }
}

// ---------------------------------------------------------------------------
// x = LayerNorm(tmp + x) * g + b; writes fp32 master (in-place) + bf16 copy
// ---------------------------------------------------------------------------
__global__ __launch_bounds__(64) void ln_kernel(const float* __restrict__ tmp,
                                                float* __restrict__ x,
                                                short* __restrict__ xb,
                                                const float* __restrict__ g,
                                                const float* __restrict__ bta) {
    const int row = blockIdx.x;
    const int t = threadIdx.x;
    const size_t base = (size_t)row * DMODEL + t * 8;
    float4 x0 = *(const float4*)(x + base);
    float4 x1 = *(const float4*)(x + base + 4);
    float4 t0 = *(const float4*)(tmp + base);
    float4 t1 = *(const float4*)(tmp + base + 4);
    float v[8];
    v[0] = x0.x + t0.x; v[1] = x0.y + t0.y; v[2] = x0.z + t0.z; v[3] = x0.w + t0.w;
    v[4] = x1.x + t1.x; v[5] = x1.y + t1.y; v[6] = x1.z + t1.z; v[7] = x1.w + t1.w;
    float s = 0.f, sq = 0.f;
#pragma unroll
    for (int i = 0; i < 8; ++i) { s += v[i]; sq += v[i] * v[i]; }
#pragma unroll
    for (int off = 1; off < 64; off <<= 1) {
        s += __shfl_xor(s, off);
        sq += __shfl_xor(sq, off);
    }
    float mu = s * (1.0f / DMODEL);
    float var = sq * (1.0f / DMODEL) - mu * mu;
    float r = rsqrtf(var + EPS);
    float4 g0 = *(const float4*)(g + t * 8);
    float4 g1 = *(const float4*)(g + t * 8 + 4);
    float4 b0 = *(const float4*)(bta + t * 8);
    float4 b1 = *(const float4*)(bta + t * 8 + 4);
    float ov[8];
    ov[0] = (v[0] - mu) * r * g0.x + b0.x;
    ov[1] = (v[1] - mu) * r * g0.y + b0.y;
    ov[2] = (v[2] - mu) * r * g0.z + b0.z;
    ov[3] = (v[3] - mu) * r * g0.w + b0.w;
    ov[4] = (v[4] - mu) * r * g1.x + b1.x;
    ov[5] = (v[5] - mu) * r * g1.y + b1.y;
    ov[6] = (v[6] - mu) * r * g1.z + b1.z;
    ov[7] = (v[7] - mu) * r * g1.w + b1.w;
    *(float4*)(x + base) = *(float4*)&ov[0];
    *(float4*)(x + base + 4) = *(float4*)&ov[4];
    bf16x8 ob;
#pragma unroll
    for (int i = 0; i < 8; ++i) ob[i] = f2bf(ov[i]);
    *(bf16x8*)(xb + base) = ob;
}

// ---------------------------------------------------------------------------
extern "C" void kernel_launch(void* const* d_in, const int* in_sizes, int n_in,
                              void* d_out, int out_size, void* d_ws, size_t ws_size,
                              hipStream_t stream) {
    const float* x_in  = (const float*)d_in[0];
    const int*   mask  = (const int*)d_in[3];
    const float* Wqkv  = (const float*)d_in[4];
    const float* Wfc   = (const float*)d_in[5];
    const float* bfc   = (const float*)d_in[6];
    const float* ln1_g = (const float*)d_in[7];
    const float* ln1_b = (const float*)d_in[8];
    const float* ln2_g = (const float*)d_in[9];
    const float* ln2_b = (const float*)d_in[10];
    const float* W1    = (const float*)d_in[11];
    const float* b1    = (const float*)d_in[12];
    const float* W2    = (const float*)d_in[13];
    const float* b2    = (const float*)d_in[14];

    float* x = (float*)d_out;  // fp32 activation master lives in d_out

    char* ws = (char*)d_ws;
    size_t ofs = 0;
    int*   pos   = (int*)ws;                 ofs += 65536;
    float* tmp   = (float*)(ws + ofs);       ofs += (size_t)ROWS * DMODEL * 4;
    short* xb    = (short*)(ws + ofs);       ofs += (size_t)ROWS * DMODEL * 2;
    short* qkvb  = (short*)(ws + ofs);
    short* hb    = (short*)(ws + ofs);       // aliases qkvb..obuf (disjoint lifetime)
    ofs += (size_t)ROWS * 3 * DMODEL * 2;
    short* obuf  = (short*)(ws + ofs);       ofs += (size_t)ROWS * DMODEL * 2;
    short* WqkvT = (short*)(ws + ofs);       ofs += (size_t)LAYERS * DMODEL * 3 * DMODEL * 2;
    short* WfcT  = (short*)(ws + ofs);       ofs += (size_t)LAYERS * DMODEL * DMODEL * 2;
    short* W1T   = (short*)(ws + ofs);       ofs += (size_t)LAYERS * DMODEL * FFDIM * 2;
    short* W2T   = (short*)(ws + ofs);       ofs += (size_t)LAYERS * FFDIM * DMODEL * 2;

    wtrans_kernel<<<dim3(3 * DMODEL / 32, DMODEL / 32, LAYERS), dim3(32, 8), 0, stream>>>(
        Wqkv, WqkvT, DMODEL, 3 * DMODEL);
    wtrans_kernel<<<dim3(DMODEL / 32, DMODEL / 32, LAYERS), dim3(32, 8), 0, stream>>>(
        Wfc, WfcT, DMODEL, DMODEL);
    wtrans_kernel<<<dim3(FFDIM / 32, DMODEL / 32, LAYERS), dim3(32, 8), 0, stream>>>(
        W1, W1T, DMODEL, FFDIM);
    wtrans_kernel<<<dim3(DMODEL / 32, FFDIM / 32, LAYERS), dim3(32, 8), 0, stream>>>(
        W2, W2T, FFDIM, DMODEL);

    pos_scan_kernel<<<BATCH, SEQ, 0, stream>>>(mask, pos);
    add_pos_kernel<<<ROWS, 128, 0, stream>>>(x_in, pos, x, xb);

    for (int l = 0; l < LAYERS; ++l) {
        const short* wqkvT_l = WqkvT + (size_t)l * DMODEL * 3 * DMODEL;
        const short* wfcT_l  = WfcT + (size_t)l * DMODEL * DMODEL;
        const short* w1T_l   = W1T + (size_t)l * DMODEL * FFDIM;
        const short* w2T_l   = W2T + (size_t)l * FFDIM * DMODEL;
        const float* bfc_l   = bfc + (size_t)l * DMODEL;
        const float* b1_l    = b1 + (size_t)l * FFDIM;
        const float* b2_l    = b2 + (size_t)l * DMODEL;

        gemm_bf16_kernel<true, false, false><<<dim3(3 * DMODEL / 128, ROWS / 128), 256, 0, stream>>>(
            xb, wqkvT_l, nullptr, qkvb, ROWS, 3 * DMODEL, DMODEL);
        attn_mfma_kernel<<<dim3(SEQ / QTILE, BATCH * NHEAD), 512, 0, stream>>>(qkvb, mask, obuf);
        gemm_bf16_kernel<false, true, false><<<dim3(DMODEL / 128, ROWS / 128), 256, 0, stream>>>(
            obuf, wfcT_l, bfc_l, tmp, ROWS, DMODEL, DMODEL);
        ln_kernel<<<ROWS, 64, 0, stream>>>(tmp, x, xb, ln1_g + (size_t)l * DMODEL,
                                           ln1_b + (size_t)l * DMODEL);
        gemm_bf16_kernel<true, true, true><<<dim3(FFDIM / 128, ROWS / 128), 256, 0, stream>>>(
            xb, w1T_l, b1_l, hb, ROWS, FFDIM, DMODEL);
        gemm_bf16_kernel<false, true, false><<<dim3(DMODEL / 128, ROWS / 128), 256, 0, stream>>>(
            hb, w2T_l, b2_l, tmp, ROWS, DMODEL, FFDIM);
        ln_kernel<<<ROWS, 64, 0, stream>>>(tmp, x, xb, ln2_g + (size_t)l * DMODEL,
                                           ln2_b + (size_t)l * DMODEL);
    }
}

// Round 5
// 1101.112 us; speedup vs baseline: 8.5676x; 1.0471x over previous
//
#include <hip/hip_runtime.h>
#include <math.h>

// Problem constants
#define LAYERS 6
#define DMODEL 512
#define NHEAD 8
#define DHEAD 64
#define FFDIM 2048
#define BATCH 8
#define SEQ 1024
#define ROWS (BATCH * SEQ)   // 8192
#define EPS 1e-5f

typedef __attribute__((ext_vector_type(8))) short bf16x8;
typedef __attribute__((ext_vector_type(4))) float f32x4;

__device__ inline short f2bf(float f) {
    union { float f; unsigned u; } v; v.f = f;
    unsigned r = (v.u + 0x7FFFu + ((v.u >> 16) & 1u)) >> 16;
    return (short)r;
}

// async global(bf16,16B) -> LDS staging; data lands at wave-uniform base + lane*16
#define GLOAD_LDS16(g, l)                                                      \
    __builtin_amdgcn_global_load_lds(                                          \
        (__attribute__((address_space(1))) void*)(g),                          \
        (__attribute__((address_space(3))) void*)(l), 16, 0, 0)

// ---------------------------------------------------------------------------
// Weight transpose + fp32->bf16: src [L][K][N] f32 -> dst [L][N][K] bf16
// ---------------------------------------------------------------------------
__global__ void wtrans_kernel(const float* __restrict__ src, short* __restrict__ dst,
                              int K, int N) {
    __shared__ float t[32][33];
    const size_t mofs = (size_t)blockIdx.z * K * N;
    src += mofs; dst += mofs;
    int n0 = blockIdx.x * 32, k0 = blockIdx.y * 32;
    int tx = threadIdx.x, ty = threadIdx.y;
#pragma unroll
    for (int i = 0; i < 4; ++i)
        t[ty + 8 * i][tx] = src[(size_t)(k0 + ty + 8 * i) * N + n0 + tx];
    __syncthreads();
#pragma unroll
    for (int i = 0; i < 4; ++i)
        dst[(size_t)(n0 + ty + 8 * i) * K + k0 + tx] = f2bf(t[tx][ty + 8 * i]);
}

// ---------------------------------------------------------------------------
// Positional scan
// ---------------------------------------------------------------------------
__global__ void pos_scan_kernel(const int* __restrict__ mask, int* __restrict__ pos) {
    __shared__ int sm[SEQ];
    int b = blockIdx.x;
    int t = threadIdx.x;
    int v = (mask[b * SEQ + t] != 0) ? 1 : 0;
    sm[t] = v;
    __syncthreads();
    for (int off = 1; off < SEQ; off <<= 1) {
        int add = (t >= off) ? sm[t - off] : 0;
        __syncthreads();
        sm[t] += add;
        __syncthreads();
    }
    pos[b * SEQ + t] = sm[t] * v;
}

// ---------------------------------------------------------------------------
// x = x_in + sin_pos_table[pos]; writes fp32 master + bf16 copy
// ---------------------------------------------------------------------------
__global__ void add_pos_kernel(const float* __restrict__ xin, const int* __restrict__ pos,
                               float* __restrict__ xout, short* __restrict__ xb) {
    int bs = blockIdx.x;
    int t = threadIdx.x;
    int p = pos[bs];
    int d0 = t * 4;
    const float C = -logf(10000.0f) * (1.0f / 255.0f);  // half-1 = 255
    float4 xv = *(const float4*)(xin + (size_t)bs * DMODEL + d0);
    float e[4];
#pragma unroll
    for (int j = 0; j < 4; ++j) {
        int d = d0 + j;
        if (p == 0) {
            e[j] = 0.0f;
        } else {
            int dd = (d < 256) ? d : d - 256;
            float freq = expf((float)dd * C);
            float ang = (float)p * freq;
            e[j] = (d < 256) ? sinf(ang) : cosf(ang);
        }
    }
    float4 ov;
    ov.x = xv.x + e[0]; ov.y = xv.y + e[1]; ov.z = xv.z + e[2]; ov.w = xv.w + e[3];
    *(float4*)(xout + (size_t)bs * DMODEL + d0) = ov;
    short4 sb;
    sb.x = f2bf(ov.x); sb.y = f2bf(ov.y); sb.z = f2bf(ov.z); sb.w = f2bf(ov.w);
    *(short4*)(xb + (size_t)bs * DMODEL + d0) = sb;
}

// ===========================================================================
// LDS k-granule swizzle (both GEMM kernels):
//   store: staging lane (r=lane>>2, pos=lane&3) fetches global granule
//          g' = (pos - (r>>1)) & 3  -> granule q of row m lands at LDS
//          position (q + ((m&15)>>1)) & 3.
//   read:  fragment (m, quad) at granule position (quad + (lr>>1)) & 3
//          (since m&15 == lr for all fragment rows).
//   Result: read bank-group (lr&1)*4 + (quad+(lr>>1))&3 covers all 8 groups
//   2-way across 16 lanes -> conflict-free (was 8-way).
// ===========================================================================

// ---------------------------------------------------------------------------
// bf16 MFMA GEMM, 128x128 tile, BK=32, 256 thr, single-barrier double-buffer.
// C[M,N] = A[M,K] @ BT[N,K]^T (+bias)(+relu).
// ---------------------------------------------------------------------------
template <bool OUTBF16, bool BIAS, bool RELU>
__global__ __launch_bounds__(256) void gemm_bf16_kernel(const short* __restrict__ A,
                                                        const short* __restrict__ BT,
                                                        const float* __restrict__ bias,
                                                        void* __restrict__ Cv,
                                                        int M, int N, int K) {
    __shared__ __attribute__((aligned(16))) short Asm[2][128 * 32];
    __shared__ __attribute__((aligned(16))) short Bsm[2][128 * 32];
    const int tid = threadIdx.x;
    const int w = tid >> 6;
    const int lane = tid & 63;
    const int quad = lane >> 4;
    const int lr = lane & 15;
    const int m0 = blockIdx.y * 128;
    const int n0 = blockIdx.x * 128;
    const int wm = (w >> 1) * 64;
    const int wn = (w & 1) * 64;

    // staging: 8 segments of 16 rows; wave w owns segs {2w, 2w+1}
    const int segr = lane >> 2;
    const int segk = (((lane & 3) - (lane >> 3)) & 3) * 8;  // swizzled source granule
    const int sA0 = w * 2, sA1 = w * 2 + 1;
    const short* gA0 = A + (size_t)(m0 + sA0 * 16 + segr) * K + segk;
    const short* gA1 = A + (size_t)(m0 + sA1 * 16 + segr) * K + segk;
    const short* gB0 = BT + (size_t)(n0 + sA0 * 16 + segr) * K + segk;
    const short* gB1 = BT + (size_t)(n0 + sA1 * 16 + segr) * K + segk;
    const int lofs0 = sA0 * 512 + lane * 8;
    const int lofs1 = sA1 * 512 + lane * 8;
    const int gp = ((quad + (lr >> 1)) & 3) * 8;            // swizzled read position

    f32x4 acc[4][4];
#pragma unroll
    for (int i = 0; i < 4; ++i)
#pragma unroll
        for (int j = 0; j < 4; ++j) { acc[i][j][0] = 0.f; acc[i][j][1] = 0.f; acc[i][j][2] = 0.f; acc[i][j][3] = 0.f; }

    GLOAD_LDS16(gA0, &Asm[0][lofs0]);
    GLOAD_LDS16(gA1, &Asm[0][lofs1]);
    GLOAD_LDS16(gB0, &Bsm[0][lofs0]);
    GLOAD_LDS16(gB1, &Bsm[0][lofs1]);

    const int nk = K >> 5;
    for (int i = 0; i < nk; ++i) {
        __syncthreads();
        if (i + 1 < nk) {
            const int k1 = (i + 1) * 32;
            const int nb = (i + 1) & 1;
            GLOAD_LDS16(gA0 + k1, &Asm[nb][lofs0]);
            GLOAD_LDS16(gA1 + k1, &Asm[nb][lofs1]);
            GLOAD_LDS16(gB0 + k1, &Bsm[nb][lofs0]);
            GLOAD_LDS16(gB1 + k1, &Bsm[nb][lofs1]);
        }
        const int cur = i & 1;
        bf16x8 af[4], bfr[4];
#pragma unroll
        for (int mt = 0; mt < 4; ++mt)
            af[mt] = *(const bf16x8*)&Asm[cur][(wm + mt * 16 + lr) * 32 + gp];
#pragma unroll
        for (int nt = 0; nt < 4; ++nt)
            bfr[nt] = *(const bf16x8*)&Bsm[cur][(wn + nt * 16 + lr) * 32 + gp];
#pragma unroll
        for (int mt = 0; mt < 4; ++mt)
#pragma unroll
            for (int nt = 0; nt < 4; ++nt)
                acc[mt][nt] = __builtin_amdgcn_mfma_f32_16x16x32_bf16(af[mt], bfr[nt], acc[mt][nt], 0, 0, 0);
    }

    float bv[4];
    if (BIAS) {
#pragma unroll
        for (int nt = 0; nt < 4; ++nt) bv[nt] = bias[n0 + wn + nt * 16 + lr];
    }
#pragma unroll
    for (int mt = 0; mt < 4; ++mt)
#pragma unroll
        for (int nt = 0; nt < 4; ++nt)
#pragma unroll
            for (int r = 0; r < 4; ++r) {
                float v = acc[mt][nt][r];
                if (BIAS) v += bv[nt];
                if (RELU) v = fmaxf(v, 0.f);
                int row = m0 + wm + mt * 16 + quad * 4 + r;
                int col = n0 + wn + nt * 16 + lr;
                if (OUTBF16)
                    ((short*)Cv)[(size_t)row * N + col] = f2bf(v);
                else
                    ((float*)Cv)[(size_t)row * N + col] = v;
            }
}

// ---------------------------------------------------------------------------
// bf16 MFMA GEMM, 64x128 tile (for N=512 GEMMs: 512 blocks = 2/CU, A streamed
// exactly once, B fits per-XCD L2). BK=32, 256 thr = 4 waves (2x2 of 32x64).
// ---------------------------------------------------------------------------
template <bool OUTBF16, bool BIAS, bool RELU>
__global__ __launch_bounds__(256) void gemm_bf16_m64_kernel(const short* __restrict__ A,
                                                            const short* __restrict__ BT,
                                                            const float* __restrict__ bias,
                                                            void* __restrict__ Cv,
                                                            int M, int N, int K) {
    __shared__ __attribute__((aligned(16))) short Asm[2][64 * 32];
    __shared__ __attribute__((aligned(16))) short Bsm[2][128 * 32];
    const int tid = threadIdx.x;
    const int w = tid >> 6;
    const int lane = tid & 63;
    const int quad = lane >> 4;
    const int lr = lane & 15;
    const int m0 = blockIdx.y * 64;
    const int n0 = blockIdx.x * 128;
    const int wm = (w >> 1) * 32;
    const int wn = (w & 1) * 64;

    // staging: A = 4 segs (wave w -> seg w), B = 8 segs (wave w -> 2w, 2w+1)
    const int segr = lane >> 2;
    const int segk = (((lane & 3) - (lane >> 3)) & 3) * 8;  // swizzled source granule
    const short* gA  = A + (size_t)(m0 + w * 16 + segr) * K + segk;
    const short* gB0 = BT + (size_t)(n0 + (2 * w) * 16 + segr) * K + segk;
    const short* gB1 = BT + (size_t)(n0 + (2 * w + 1) * 16 + segr) * K + segk;
    const int lA  = w * 512 + lane * 8;
    const int lB0 = (2 * w) * 512 + lane * 8;
    const int lB1 = (2 * w + 1) * 512 + lane * 8;
    const int gp = ((quad + (lr >> 1)) & 3) * 8;            // swizzled read position

    f32x4 acc[2][4];
#pragma unroll
    for (int i = 0; i < 2; ++i)
#pragma unroll
        for (int j = 0; j < 4; ++j) { acc[i][j][0] = 0.f; acc[i][j][1] = 0.f; acc[i][j][2] = 0.f; acc[i][j][3] = 0.f; }

    GLOAD_LDS16(gA, &Asm[0][lA]);
    GLOAD_LDS16(gB0, &Bsm[0][lB0]);
    GLOAD_LDS16(gB1, &Bsm[0][lB1]);

    const int nk = K >> 5;
    for (int i = 0; i < nk; ++i) {
        __syncthreads();
        if (i + 1 < nk) {
            const int k1 = (i + 1) * 32;
            const int nb = (i + 1) & 1;
            GLOAD_LDS16(gA + k1, &Asm[nb][lA]);
            GLOAD_LDS16(gB0 + k1, &Bsm[nb][lB0]);
            GLOAD_LDS16(gB1 + k1, &Bsm[nb][lB1]);
        }
        const int cur = i & 1;
        bf16x8 af[2], bfr[4];
#pragma unroll
        for (int mt = 0; mt < 2; ++mt)
            af[mt] = *(const bf16x8*)&Asm[cur][(wm + mt * 16 + lr) * 32 + gp];
#pragma unroll
        for (int nt = 0; nt < 4; ++nt)
            bfr[nt] = *(const bf16x8*)&Bsm[cur][(wn + nt * 16 + lr) * 32 + gp];
#pragma unroll
        for (int mt = 0; mt < 2; ++mt)
#pragma unroll
            for (int nt = 0; nt < 4; ++nt)
                acc[mt][nt] = __builtin_amdgcn_mfma_f32_16x16x32_bf16(af[mt], bfr[nt], acc[mt][nt], 0, 0, 0);
    }

    float bv[4];
    if (BIAS) {
#pragma unroll
        for (int nt = 0; nt < 4; ++nt) bv[nt] = bias[n0 + wn + nt * 16 + lr];
    }
#pragma unroll
    for (int mt = 0; mt < 2; ++mt)
#pragma unroll
        for (int nt = 0; nt < 4; ++nt)
#pragma unroll
            for (int r = 0; r < 4; ++r) {
                float v = acc[mt][nt][r];
                if (BIAS) v += bv[nt];
                if (RELU) v = fmaxf(v, 0.f);
                int row = m0 + wm + mt * 16 + quad * 4 + r;
                int col = n0 + wn + nt * 16 + lr;
                if (OUTBF16)
                    ((short*)Cv)[(size_t)row * N + col] = f2bf(v);
                else
                    ((float*)Cv)[(size_t)row * N + col] = v;
            }
}

// ---------------------------------------------------------------------------
// bf16-MFMA flash attention v2: QTILE=256 (512 thr = 8 waves, 32 q-rows each),
// no-rescale softmax (fixed shift 8, exact after normalization), double-
// buffered K/V staging with ONE barrier per tile, conflict-free V-transpose.
// ---------------------------------------------------------------------------
#define QTILE 256
__global__ __launch_bounds__(512) void attn_mfma_kernel(const short* __restrict__ qkv,
                                                        const int* __restrict__ mask,
                                                        short* __restrict__ o) {
    __shared__ __attribute__((aligned(16))) short Ks[2][64][72];    // [key][d]
    __shared__ __attribute__((aligned(16))) short Vt[2][64][72];    // [d][key]
    __shared__ __attribute__((aligned(16))) short Ps[8][16][72];    // per-wave P[m][key]
    __shared__ float Msf[2][64];

    const int qt = blockIdx.x;          // 0..3
    const int bh = blockIdx.y;          // 0..63
    const int b = bh >> 3, h = bh & 7;
    const int tid = threadIdx.x;
    const int w = tid >> 6;             // wave 0..7
    const int lane = tid & 63;
    const int quad = lane >> 4;
    const int lr = lane & 15;
    const size_t seqrow = (size_t)b * SEQ;

    bf16x8 qf[2][2];
#pragma unroll
    for (int mt = 0; mt < 2; ++mt)
#pragma unroll
        for (int c = 0; c < 2; ++c)
            qf[mt][c] = *(const bf16x8*)(qkv +
                (seqrow + qt * QTILE + w * 32 + mt * 16 + lr) * (3 * DMODEL)
                + h * DHEAD + c * 32 + quad * 8);

    const bool isK = (tid < 256);
    const int st = isK ? tid : tid - 256;
    const int kkey = st >> 2;
    const int kg = (st & 3) * 8;
    const int vkp = st & 31;
    const int vdg = st >> 5;
    const short* gK = qkv + (seqrow + kkey) * (3 * DMODEL) + DMODEL + h * DHEAD + kg;
    const short* gV = qkv + (seqrow + 2 * vkp) * (3 * DMODEL) + 2 * DMODEL + h * DHEAD + vdg * 8;

    bf16x8 r0, r1;
    int mreg = 0;

    {
        if (isK) {
            r0 = *(const bf16x8*)(gK);
            r1 = *(const bf16x8*)(gK + 32);
        } else {
            r0 = *(const bf16x8*)(gV);
            r1 = *(const bf16x8*)(gV + 3 * DMODEL);
        }
        if (tid < 64) mreg = mask[seqrow + tid];
        if (isK) {
            *(bf16x8*)&Ks[0][kkey][kg] = r0;
            *(bf16x8*)&Ks[0][kkey][kg + 32] = r1;
        } else {
#pragma unroll
            for (int i = 0; i < 8; ++i) {
                short2 p; p.x = r0[i]; p.y = r1[i];
                *(short2*)&Vt[0][vdg * 8 + i][vkp * 2] = p;
            }
        }
        if (tid < 64) Msf[0][tid] = mreg ? 1.0f : 0.0f;
    }
    __syncthreads();

    f32x4 Oacc[2][4];
    float rs[2][4];
#pragma unroll
    for (int mt = 0; mt < 2; ++mt)
#pragma unroll
        for (int t2 = 0; t2 < 4; ++t2) { Oacc[mt][t2][0] = 0.f; Oacc[mt][t2][1] = 0.f; Oacc[mt][t2][2] = 0.f; Oacc[mt][t2][3] = 0.f; }
#pragma unroll
    for (int mt = 0; mt < 2; ++mt)
#pragma unroll
        for (int r = 0; r < 4; ++r) rs[mt][r] = 0.f;

    for (int kt = 0; kt < 16; ++kt) {
        const int cur = kt & 1;
        {
            const size_t ofs = (size_t)((kt + 1) & 15) * 64 * (3 * DMODEL);
            if (isK) {
                r0 = *(const bf16x8*)(gK + ofs);
                r1 = *(const bf16x8*)(gK + ofs + 32);
            } else {
                r0 = *(const bf16x8*)(gV + ofs);
                r1 = *(const bf16x8*)(gV + ofs + 3 * DMODEL);
            }
            if (tid < 64) mreg = mask[seqrow + ((kt + 1) & 15) * 64 + tid];
        }
        bf16x8 kf[2][4], vf[2][4];
#pragma unroll
        for (int c = 0; c < 2; ++c)
#pragma unroll
            for (int t = 0; t < 4; ++t) {
                kf[c][t] = *(const bf16x8*)&Ks[cur][lr + 16 * t][quad * 8 + 32 * c];
                vf[c][t] = *(const bf16x8*)&Vt[cur][lr + 16 * t][quad * 8 + 32 * c];
            }
        float mv[4];
#pragma unroll
        for (int t = 0; t < 4; ++t) mv[t] = Msf[cur][lr + 16 * t];

#pragma unroll
        for (int mt = 0; mt < 2; ++mt) {
            f32x4 S[4];
#pragma unroll
            for (int t = 0; t < 4; ++t) { S[t][0] = 0.f; S[t][1] = 0.f; S[t][2] = 0.f; S[t][3] = 0.f; }
#pragma unroll
            for (int c = 0; c < 2; ++c)
#pragma unroll
                for (int t = 0; t < 4; ++t)
                    S[t] = __builtin_amdgcn_mfma_f32_16x16x32_bf16(qf[mt][c], kf[c][t], S[t], 0, 0, 0);
#pragma unroll
            for (int t = 0; t < 4; ++t)
#pragma unroll
                for (int r = 0; r < 4; ++r) {
                    float p = __expf(S[t][r] - 8.0f) * mv[t];
                    S[t][r] = p;
                    rs[mt][r] += p;
                }
#pragma unroll
            for (int t = 0; t < 4; ++t)
#pragma unroll
                for (int r = 0; r < 4; ++r)
                    Ps[w][quad * 4 + r][lr + 16 * t] = f2bf(S[t][r]);
            bf16x8 pa0 = *(const bf16x8*)&Ps[w][lr][quad * 8];
            bf16x8 pa1 = *(const bf16x8*)&Ps[w][lr][quad * 8 + 32];
#pragma unroll
            for (int t2 = 0; t2 < 4; ++t2) {
                Oacc[mt][t2] = __builtin_amdgcn_mfma_f32_16x16x32_bf16(pa0, vf[0][t2], Oacc[mt][t2], 0, 0, 0);
                Oacc[mt][t2] = __builtin_amdgcn_mfma_f32_16x16x32_bf16(pa1, vf[1][t2], Oacc[mt][t2], 0, 0, 0);
            }
        }
        {
            const int nb = cur ^ 1;
            if (isK) {
                *(bf16x8*)&Ks[nb][kkey][kg] = r0;
                *(bf16x8*)&Ks[nb][kkey][kg + 32] = r1;
            } else {
#pragma unroll
                for (int i = 0; i < 8; ++i) {
                    short2 p; p.x = r0[i]; p.y = r1[i];
                    *(short2*)&Vt[nb][vdg * 8 + i][vkp * 2] = p;
                }
            }
            if (tid < 64) Msf[nb][tid] = mreg ? 1.0f : 0.0f;
        }
        __syncthreads();
    }

#pragma unroll
    for (int mt = 0; mt < 2; ++mt) {
        float inv[4];
#pragma unroll
        for (int r = 0; r < 4; ++r) {
            float v = rs[mt][r];
            v += __shfl_xor(v, 1);
            v += __shfl_xor(v, 2);
            v += __shfl_xor(v, 4);
            v += __shfl_xor(v, 8);
            inv[r] = 1.f / v;
        }
#pragma unroll
        for (int t2 = 0; t2 < 4; ++t2)
#pragma unroll
            for (int r = 0; r < 4; ++r) {
                int row = qt * QTILE + w * 32 + mt * 16 + quad * 4 + r;
                o[(seqrow + row) * DMODEL + h * DHEAD + 16 * t2 + lr] = f2bf(Oacc[mt][t2][r] * inv[r]);
            }
    }
}

// ---------------------------------------------------------------------------
// x = LayerNorm(tmp + x) * g + b; writes fp32 master (in-place) + bf16 copy
// ---------------------------------------------------------------------------
__global__ __launch_bounds__(64) void ln_kernel(const float* __restrict__ tmp,
                                                float* __restrict__ x,
                                                short* __restrict__ xb,
                                                const float* __restrict__ g,
                                                const float* __restrict__ bta) {
    const int row = blockIdx.x;
    const int t = threadIdx.x;
    const size_t base = (size_t)row * DMODEL + t * 8;
    float4 x0 = *(const float4*)(x + base);
    float4 x1 = *(const float4*)(x + base + 4);
    float4 t0 = *(const float4*)(tmp + base);
    float4 t1 = *(const float4*)(tmp + base + 4);
    float v[8];
    v[0] = x0.x + t0.x; v[1] = x0.y + t0.y; v[2] = x0.z + t0.z; v[3] = x0.w + t0.w;
    v[4] = x1.x + t1.x; v[5] = x1.y + t1.y; v[6] = x1.z + t1.z; v[7] = x1.w + t1.w;
    float s = 0.f, sq = 0.f;
#pragma unroll
    for (int i = 0; i < 8; ++i) { s += v[i]; sq += v[i] * v[i]; }
#pragma unroll
    for (int off = 1; off < 64; off <<= 1) {
        s += __shfl_xor(s, off);
        sq += __shfl_xor(sq, off);
    }
    float mu = s * (1.0f / DMODEL);
    float var = sq * (1.0f / DMODEL) - mu * mu;
    float r = rsqrtf(var + EPS);
    float4 g0 = *(const float4*)(g + t * 8);
    float4 g1 = *(const float4*)(g + t * 8 + 4);
    float4 b0 = *(const float4*)(bta + t * 8);
    float4 b1 = *(const float4*)(bta + t * 8 + 4);
    float ov[8];
    ov[0] = (v[0] - mu) * r * g0.x + b0.x;
    ov[1] = (v[1] - mu) * r * g0.y + b0.y;
    ov[2] = (v[2] - mu) * r * g0.z + b0.z;
    ov[3] = (v[3] - mu) * r * g0.w + b0.w;
    ov[4] = (v[4] - mu) * r * g1.x + b1.x;
    ov[5] = (v[5] - mu) * r * g1.y + b1.y;
    ov[6] = (v[6] - mu) * r * g1.z + b1.z;
    ov[7] = (v[7] - mu) * r * g1.w + b1.w;
    *(float4*)(x + base) = *(float4*)&ov[0];
    *(float4*)(x + base + 4) = *(float4*)&ov[4];
    bf16x8 ob;
#pragma unroll
    for (int i = 0; i < 8; ++i) ob[i] = f2bf(ov[i]);
    *(bf16x8*)(xb + base) = ob;
}

// ---------------------------------------------------------------------------
extern "C" void kernel_launch(void* const* d_in, const int* in_sizes, int n_in,
                              void* d_out, int out_size, void* d_ws, size_t ws_size,
                              hipStream_t stream) {
    const float* x_in  = (const float*)d_in[0];
    const int*   mask  = (const int*)d_in[3];
    const float* Wqkv  = (const float*)d_in[4];
    const float* Wfc   = (const float*)d_in[5];
    const float* bfc   = (const float*)d_in[6];
    const float* ln1_g = (const float*)d_in[7];
    const float* ln1_b = (const float*)d_in[8];
    const float* ln2_g = (const float*)d_in[9];
    const float* ln2_b = (const float*)d_in[10];
    const float* W1    = (const float*)d_in[11];
    const float* b1    = (const float*)d_in[12];
    const float* W2    = (const float*)d_in[13];
    const float* b2    = (const float*)d_in[14];

    float* x = (float*)d_out;  // fp32 activation master lives in d_out

    char* ws = (char*)d_ws;
    size_t ofs = 0;
    int*   pos   = (int*)ws;                 ofs += 65536;
    float* tmp   = (float*)(ws + ofs);       ofs += (size_t)ROWS * DMODEL * 4;
    short* xb    = (short*)(ws + ofs);       ofs += (size_t)ROWS * DMODEL * 2;
    short* qkvb  = (short*)(ws + ofs);
    short* hb    = (short*)(ws + ofs);       // aliases qkvb..obuf (disjoint lifetime)
    ofs += (size_t)ROWS * 3 * DMODEL * 2;
    short* obuf  = (short*)(ws + ofs);       ofs += (size_t)ROWS * DMODEL * 2;
    short* WqkvT = (short*)(ws + ofs);       ofs += (size_t)LAYERS * DMODEL * 3 * DMODEL * 2;
    short* WfcT  = (short*)(ws + ofs);       ofs += (size_t)LAYERS * DMODEL * DMODEL * 2;
    short* W1T   = (short*)(ws + ofs);       ofs += (size_t)LAYERS * DMODEL * FFDIM * 2;
    short* W2T   = (short*)(ws + ofs);       ofs += (size_t)LAYERS * FFDIM * DMODEL * 2;

    wtrans_kernel<<<dim3(3 * DMODEL / 32, DMODEL / 32, LAYERS), dim3(32, 8), 0, stream>>>(
        Wqkv, WqkvT, DMODEL, 3 * DMODEL);
    wtrans_kernel<<<dim3(DMODEL / 32, DMODEL / 32, LAYERS), dim3(32, 8), 0, stream>>>(
        Wfc, WfcT, DMODEL, DMODEL);
    wtrans_kernel<<<dim3(FFDIM / 32, DMODEL / 32, LAYERS), dim3(32, 8), 0, stream>>>(
        W1, W1T, DMODEL, FFDIM);
    wtrans_kernel<<<dim3(DMODEL / 32, FFDIM / 32, LAYERS), dim3(32, 8), 0, stream>>>(
        W2, W2T, FFDIM, DMODEL);

    pos_scan_kernel<<<BATCH, SEQ, 0, stream>>>(mask, pos);
    add_pos_kernel<<<ROWS, 128, 0, stream>>>(x_in, pos, x, xb);

    for (int l = 0; l < LAYERS; ++l) {
        const short* wqkvT_l = WqkvT + (size_t)l * DMODEL * 3 * DMODEL;
        const short* wfcT_l  = WfcT + (size_t)l * DMODEL * DMODEL;
        const short* w1T_l   = W1T + (size_t)l * DMODEL * FFDIM;
        const short* w2T_l   = W2T + (size_t)l * FFDIM * DMODEL;
        const float* bfc_l   = bfc + (size_t)l * DMODEL;
        const float* b1_l    = b1 + (size_t)l * FFDIM;
        const float* b2_l    = b2 + (size_t)l * DMODEL;

        // qkv = x @ Wqkv  (bf16 out), N=1536: 768 blocks
        gemm_bf16_kernel<true, false, false><<<dim3(3 * DMODEL / 128, ROWS / 128), 256, 0, stream>>>(
            xb, wqkvT_l, nullptr, qkvb, ROWS, 3 * DMODEL, DMODEL);
        attn_mfma_kernel<<<dim3(SEQ / QTILE, BATCH * NHEAD), 512, 0, stream>>>(qkvb, mask, obuf);
        // tmp = obuf @ Wfc + bfc  (fp32 out), N=512: m64 tile -> 512 blocks
        gemm_bf16_m64_kernel<false, true, false><<<dim3(DMODEL / 128, ROWS / 64), 256, 0, stream>>>(
            obuf, wfcT_l, bfc_l, tmp, ROWS, DMODEL, DMODEL);
        ln_kernel<<<ROWS, 64, 0, stream>>>(tmp, x, xb, ln1_g + (size_t)l * DMODEL,
                                           ln1_b + (size_t)l * DMODEL);
        // h = relu(x @ W1 + b1)  (bf16 out), N=2048: 1024 blocks
        gemm_bf16_kernel<true, true, true><<<dim3(FFDIM / 128, ROWS / 128), 256, 0, stream>>>(
            xb, w1T_l, b1_l, hb, ROWS, FFDIM, DMODEL);
        // tmp = h @ W2 + b2  (fp32 out), N=512: m64 tile -> 512 blocks
        gemm_bf16_m64_kernel<false, true, false><<<dim3(DMODEL / 128, ROWS / 64), 256, 0, stream>>>(
            hb, w2T_l, b2_l, tmp, ROWS, DMODEL, FFDIM);
        ln_kernel<<<ROWS, 64, 0, stream>>>(tmp, x, xb, ln2_g + (size_t)l * DMODEL,
                                           ln2_b + (size_t)l * DMODEL);
    }
}